// Round 1
// baseline (2980.843 us; speedup 1.0000x reference)
//
#include <hip/hip_runtime.h>
#include <hip/hip_bf16.h>

#define L_SEQ 2048
#define DMODEL 1024
#define DIN 2048
#define DTR 64
#define NST 16

// ---------------- generic fp32 tiled GEMM: C[M,N] = A[M,K] * B[K,N] ----------------
#define BM 64
#define BN 64
#define BK 16

__global__ __launch_bounds__(256) void gemm_f32(const float* __restrict__ A,
                                                const float* __restrict__ B,
                                                float* __restrict__ C,
                                                int M, int N, int K,
                                                int lda, int ldb, int ldc) {
    __shared__ float As[BK][BM + 1];   // transposed store: As[k][m]
    __shared__ float Bs[BK][BN + 1];
    const int tid = threadIdx.x;
    const int bm = blockIdx.y * BM;
    const int bn = blockIdx.x * BN;
    const int ty = tid >> 4;   // 0..15
    const int tx = tid & 15;   // 0..15

    float acc[4][4] = {};

    for (int k0 = 0; k0 < K; k0 += BK) {
#pragma unroll
        for (int i = 0; i < 4; ++i) {
            int idx = tid + i * 256;         // 0..1023
            int r = idx >> 4;                // /BK  (0..63)
            int c = idx & 15;                // %BK
            int gr = bm + r, gc = k0 + c;
            As[c][r] = (gr < M && gc < K) ? A[gr * lda + gc] : 0.f;
        }
#pragma unroll
        for (int i = 0; i < 4; ++i) {
            int idx = tid + i * 256;
            int r = idx >> 6;                // /BN (0..15)
            int c = idx & 63;                // %BN
            int gr = k0 + r, gc = bn + c;
            Bs[r][c] = (gr < K && gc < N) ? B[gr * ldb + gc] : 0.f;
        }
        __syncthreads();
#pragma unroll
        for (int kk = 0; kk < BK; ++kk) {
            float a[4], b[4];
#pragma unroll
            for (int i = 0; i < 4; ++i) a[i] = As[kk][ty * 4 + i];
#pragma unroll
            for (int j = 0; j < 4; ++j) b[j] = Bs[kk][tx * 4 + j];
#pragma unroll
            for (int i = 0; i < 4; ++i)
#pragma unroll
                for (int j = 0; j < 4; ++j) acc[i][j] += a[i] * b[j];
        }
        __syncthreads();
    }

#pragma unroll
    for (int i = 0; i < 4; ++i) {
        int gr = bm + ty * 4 + i;
        if (gr >= M) continue;
#pragma unroll
        for (int j = 0; j < 4; ++j) {
            int gc = bn + tx * 4 + j;
            if (gc < N) C[gr * ldc + gc] = acc[i][j];
        }
    }
}

// ---------------- causal depthwise conv(4) + bias + swish ----------------
// xr: (L, 4096) — cols 0..2047 are xi_raw. Output xi: (L, 2048)
__global__ __launch_bounds__(256) void conv_swish(const float* __restrict__ xr,
                                                  const float* __restrict__ cw,
                                                  const float* __restrict__ cb,
                                                  float* __restrict__ xi) {
    int id = blockIdx.x * 256 + threadIdx.x;       // 0 .. L*DIN-1
    int l = id >> 11;
    int d = id & (DIN - 1);
    float acc = cb[d];
#pragma unroll
    for (int k = 0; k < 4; ++k) {
        int ls = l - 3 + k;
        if (ls >= 0) acc += xr[ls * 4096 + d] * cw[k * DIN + d];
    }
    float sw = acc / (1.f + expf(-acc));           // swish
    xi[id] = sw;
}

// ---------------- delta = softplus(x_dbl[:, :64] @ W_dt + b_dt) ----------------
// one block per row l; 256 threads x 8 cols each
__global__ __launch_bounds__(256) void delta_kernel(const float* __restrict__ xdbl,
                                                    const float* __restrict__ Wdt,
                                                    const float* __restrict__ bdt,
                                                    float* __restrict__ delta) {
    __shared__ float dr[DTR];
    int l = blockIdx.x;
    int t = threadIdx.x;
    if (t < DTR) dr[t] = xdbl[l * 96 + t];
    __syncthreads();
#pragma unroll
    for (int j = 0; j < 8; ++j) {
        int col = t + j * 256;
        float acc = bdt[col];
#pragma unroll
        for (int k = 0; k < DTR; ++k) acc += dr[k] * Wdt[k * DIN + col];
        float sp = (acc > 20.f) ? acc : log1pf(expf(acc));
        delta[l * DIN + col] = sp;
    }
}

// ---------------- column sums of delta (per-d total), double accumulation ----------------
// block: 32 cols x 8 row-chunks of 256
__global__ __launch_bounds__(256) void colsum_kernel(const float* __restrict__ delta,
                                                     float* __restrict__ Stot) {
    __shared__ double sh[256];
    int t = threadIdx.x;
    int col = blockIdx.x * 32 + (t & 31);
    int chunk = t >> 5;
    double s = 0.0;
    int l0 = chunk * 256;
    for (int l = l0; l < l0 + 256; ++l) s += (double)delta[l * DIN + col];
    sh[t] = s;
    __syncthreads();
    if (chunk == 0) {
        double tot = 0.0;
        for (int c = 0; c < 8; ++c) tot += sh[c * 32 + (t & 31)];
        Stot[col] = (float)tot;
    }
}

// ---------------- selective scan (replicates reference eps/cumsum semantics) --------
// thread = (d, n): lane groups of 16 share d. Writes gated output in place over u.
__global__ __launch_bounds__(256) void scan_kernel(const float* __restrict__ delta,
                                                   float* __restrict__ u,      // xi; overwritten with ygated
                                                   const float* __restrict__ xdbl,
                                                   const float* __restrict__ Stot,
                                                   const float* __restrict__ Dvec,
                                                   const float* __restrict__ xr) {
    int gid = blockIdx.x * 256 + threadIdx.x;   // 0 .. 32767
    int d = gid >> 4;
    int n = gid & 15;
    const float An = -(float)(n + 1);
    const float stot = Stot[d];
    const float Dd = Dvec[d];
    double S = 0.0;
    double Nacc = 0.0;
    const float* Bbase = xdbl + DTR;        // cols 64..79
    const float* Cbase = xdbl + DTR + NST;  // cols 80..95

#pragma unroll 4
    for (int l = 0; l < L_SEQ; ++l) {
        float dl = delta[l * DIN + d];
        float ul = u[l * DIN + d];
        float Bv = Bbase[l * 96 + n];
        float Cv = Cbase[l * 96 + n];
        S += (double)dl;
        float T = An * (float)((double)stot - S);
        float e = expf(T);                  // dA_cs
        Nacc += (double)(dl * ul * Bv * e);
        float xs = (float)Nacc / (e + 1e-12f);
        float contrib = xs * Cv;
        contrib += __shfl_xor(contrib, 1, 16);
        contrib += __shfl_xor(contrib, 2, 16);
        contrib += __shfl_xor(contrib, 4, 16);
        contrib += __shfl_xor(contrib, 8, 16);
        if (n == 0) {
            float y = contrib + ul * Dd;
            float r = xr[l * 4096 + DIN + d];        // res
            float sw = r / (1.f + expf(-r));
            u[l * DIN + d] = y * sw;                 // gated output (in place; read-before-write in lockstep wave)
        }
    }
}

extern "C" void kernel_launch(void* const* d_in, const int* in_sizes, int n_in,
                              void* d_out, int out_size, void* d_ws, size_t ws_size,
                              hipStream_t stream) {
    const float* x      = (const float*)d_in[0];   // (1, 2048, 1024)
    const float* W_in   = (const float*)d_in[1];   // (1024, 4096)
    const float* conv_w = (const float*)d_in[2];   // (4, 2048)
    const float* conv_b = (const float*)d_in[3];   // (2048,)
    const float* W_x    = (const float*)d_in[4];   // (2048, 96)
    const float* W_dt   = (const float*)d_in[5];   // (64, 2048)
    const float* b_dt   = (const float*)d_in[6];   // (2048,)
    const float* Dvec   = (const float*)d_in[7];   // (2048,)
    const float* W_out  = (const float*)d_in[8];   // (2048, 1024)
    float* out = (float*)d_out;                    // (1, 2048, 1024)

    char* ws = (char*)d_ws;
    float* xr    = (float*)(ws);                                  // 2048*4096
    float* xi    = (float*)(ws + (size_t)L_SEQ * 4096 * 4);       // 2048*2048 (u, then ygated)
    float* xdbl  = (float*)(ws + (size_t)L_SEQ * 4096 * 4
                               + (size_t)L_SEQ * DIN * 4);        // 2048*96
    float* delta = (float*)(ws + (size_t)L_SEQ * 4096 * 4
                               + (size_t)L_SEQ * DIN * 4
                               + (size_t)L_SEQ * 96 * 4);         // 2048*2048
    float* Stot  = (float*)(ws + (size_t)L_SEQ * 4096 * 4
                               + (size_t)L_SEQ * DIN * 4
                               + (size_t)L_SEQ * 96 * 4
                               + (size_t)L_SEQ * DIN * 4);        // 2048

    // 1) xr = x @ W_in    (M=2048, N=4096, K=1024)
    {
        dim3 grid(4096 / BN, L_SEQ / BM);
        gemm_f32<<<grid, 256, 0, stream>>>(x, W_in, xr, L_SEQ, 4096, DMODEL,
                                           DMODEL, 4096, 4096);
    }
    // 2) xi = swish(causal_conv(xr[:, :2048]))
    {
        int nthreads = L_SEQ * DIN;
        conv_swish<<<nthreads / 256, 256, 0, stream>>>(xr, conv_w, conv_b, xi);
    }
    // 3) xdbl = xi @ W_x  (M=2048, N=96, K=2048)
    {
        dim3 grid((96 + BN - 1) / BN, L_SEQ / BM);
        gemm_f32<<<grid, 256, 0, stream>>>(xi, W_x, xdbl, L_SEQ, 96, DIN,
                                           DIN, 96, 96);
    }
    // 4) delta = softplus(xdbl[:, :64] @ W_dt + b_dt)
    delta_kernel<<<L_SEQ, 256, 0, stream>>>(xdbl, W_dt, b_dt, delta);
    // 5) per-d totals of delta
    colsum_kernel<<<DIN / 32, 256, 0, stream>>>(delta, Stot);
    // 6) selective scan + gate (in place into xi)
    scan_kernel<<<(DIN * NST) / 256, 256, 0, stream>>>(delta, xi, xdbl, Stot, Dvec, xr);
    // 7) out = ygated @ W_out (M=2048, N=1024, K=2048)
    {
        dim3 grid(DMODEL / BN, L_SEQ / BM);
        gemm_f32<<<grid, 256, 0, stream>>>(xi, W_out, out, L_SEQ, DMODEL, DIN,
                                           DIN, DMODEL, DMODEL);
    }
}

// Round 2
// 1370.259 us; speedup vs baseline: 2.1754x; 2.1754x over previous
//
#include <hip/hip_runtime.h>
#include <hip/hip_bf16.h>

#define L_SEQ 2048
#define DMODEL 1024
#define DIN 2048
#define DTR 64
#define NST 16
#define CCH 16          // number of chunks
#define CHL 128         // L_SEQ / CCH

// ---------------- generic fp32 tiled GEMM: C[M,N] = A[M,K] * B[K,N] ----------------
#define BM 64
#define BN 64
#define BK 16

__global__ __launch_bounds__(256) void gemm_f32(const float* __restrict__ A,
                                                const float* __restrict__ B,
                                                float* __restrict__ C,
                                                int M, int N, int K,
                                                int lda, int ldb, int ldc) {
    __shared__ float As[BK][BM + 1];   // transposed store: As[k][m]
    __shared__ float Bs[BK][BN + 1];
    const int tid = threadIdx.x;
    const int bm = blockIdx.y * BM;
    const int bn = blockIdx.x * BN;
    const int ty = tid >> 4;   // 0..15
    const int tx = tid & 15;   // 0..15

    float acc[4][4] = {};

    for (int k0 = 0; k0 < K; k0 += BK) {
#pragma unroll
        for (int i = 0; i < 4; ++i) {
            int idx = tid + i * 256;         // 0..1023
            int r = idx >> 4;                // /BK  (0..63)
            int c = idx & 15;                // %BK
            int gr = bm + r, gc = k0 + c;
            As[c][r] = (gr < M && gc < K) ? A[gr * lda + gc] : 0.f;
        }
#pragma unroll
        for (int i = 0; i < 4; ++i) {
            int idx = tid + i * 256;
            int r = idx >> 6;                // /BN (0..15)
            int c = idx & 63;                // %BN
            int gr = k0 + r, gc = bn + c;
            Bs[r][c] = (gr < K && gc < N) ? B[gr * ldb + gc] : 0.f;
        }
        __syncthreads();
#pragma unroll
        for (int kk = 0; kk < BK; ++kk) {
            float a[4], b[4];
#pragma unroll
            for (int i = 0; i < 4; ++i) a[i] = As[kk][ty * 4 + i];
#pragma unroll
            for (int j = 0; j < 4; ++j) b[j] = Bs[kk][tx * 4 + j];
#pragma unroll
            for (int i = 0; i < 4; ++i)
#pragma unroll
                for (int j = 0; j < 4; ++j) acc[i][j] += a[i] * b[j];
        }
        __syncthreads();
    }

#pragma unroll
    for (int i = 0; i < 4; ++i) {
        int gr = bm + ty * 4 + i;
        if (gr >= M) continue;
#pragma unroll
        for (int j = 0; j < 4; ++j) {
            int gc = bn + tx * 4 + j;
            if (gc < N) C[gr * ldc + gc] = acc[i][j];
        }
    }
}

// ---------------- causal depthwise conv(4) + bias + swish ----------------
__global__ __launch_bounds__(256) void conv_swish(const float* __restrict__ xr,
                                                  const float* __restrict__ cw,
                                                  const float* __restrict__ cb,
                                                  float* __restrict__ xi) {
    int id = blockIdx.x * 256 + threadIdx.x;       // 0 .. L*DIN-1
    int l = id >> 11;
    int d = id & (DIN - 1);
    float acc = cb[d];
#pragma unroll
    for (int k = 0; k < 4; ++k) {
        int ls = l - 3 + k;
        if (ls >= 0) acc += xr[ls * 4096 + d] * cw[k * DIN + d];
    }
    float sw = acc / (1.f + expf(-acc));           // swish
    xi[id] = sw;
}

// ---------------- delta = softplus(x_dbl[:, :64] @ W_dt + b_dt) ----------------
__global__ __launch_bounds__(256) void delta_kernel(const float* __restrict__ xdbl,
                                                    const float* __restrict__ Wdt,
                                                    const float* __restrict__ bdt,
                                                    float* __restrict__ delta) {
    __shared__ float dr[DTR];
    int l = blockIdx.x;
    int t = threadIdx.x;
    if (t < DTR) dr[t] = xdbl[l * 96 + t];
    __syncthreads();
#pragma unroll
    for (int j = 0; j < 8; ++j) {
        int col = t + j * 256;
        float acc = bdt[col];
#pragma unroll
        for (int k = 0; k < DTR; ++k) acc += dr[k] * Wdt[k * DIN + col];
        float sp = (acc > 20.f) ? acc : log1pf(expf(acc));
        delta[l * DIN + col] = sp;
    }
}

// ---------------- chunk-parallel selective scan ----------------
// Identity used: q_l := Nacc_l / e_l obeys q_l = q_{l-1}*exp(An*d_l) + d_l*u_l*B_l;
// xs_l = q_l * e_l/(e_l + 1e-12), e_l = exp(An * suffix_l), suffix_l = sum_{k>l} d_k.

// pass A: per (d,n,chunk) local recurrence from q=0
__global__ __launch_bounds__(256) void scan_passA(const float* __restrict__ delta,
                                                  const float* __restrict__ u,
                                                  const float* __restrict__ xdbl,
                                                  float* __restrict__ localQ,
                                                  float* __restrict__ Wfac,
                                                  float* __restrict__ chunkSum) {
    int gid = blockIdx.x * 256 + threadIdx.x;     // 0 .. DIN*NST*CCH-1
    int n = gid & 15;
    int d = (gid >> 4) & (DIN - 1);
    int c = gid >> 15;
    const float An = -(float)(n + 1);
    const float* Bbase = xdbl + DTR;
    float q = 0.f;
    float s = 0.f;
    int l0 = c * CHL;
#pragma unroll 4
    for (int l = l0; l < l0 + CHL; ++l) {
        float dl = delta[l * DIN + d];
        float ul = u[l * DIN + d];
        float Bv = Bbase[l * 96 + n];
        float e = expf(An * dl);
        q = q * e + dl * ul * Bv;
        s += dl;
    }
    int idx = (c * DIN + d) * 16 + n;
    localQ[idx] = q;
    Wfac[idx] = expf(An * s);
    if (n == 0) chunkSum[c * DIN + d] = s;
}

// pass B: cross-chunk combine (q_start per chunk) + suffix offsets per d
__global__ __launch_bounds__(256) void scan_passB(const float* __restrict__ localQ,
                                                  const float* __restrict__ Wfac,
                                                  float* __restrict__ qstart,
                                                  const float* __restrict__ chunkSum,
                                                  float* __restrict__ SuffOff) {
    int gid = blockIdx.x * 256 + threadIdx.x;     // 0 .. DIN*NST-1
    int n = gid & 15;
    int d = gid >> 4;
    float q = 0.f;
#pragma unroll
    for (int c = 0; c < CCH; ++c) {
        int idx = (c * DIN + d) * 16 + n;
        qstart[idx] = q;
        q = q * Wfac[idx] + localQ[idx];
    }
    if (n == 0) {
        double s = 0.0;
#pragma unroll
        for (int c = CCH - 1; c >= 0; --c) {
            SuffOff[c * DIN + d] = (float)s;      // sum of deltas in chunks AFTER c
            s += (double)chunkSum[c * DIN + d];
        }
    }
}

// pass C: replay chunk with correct q_start, eps-correction, n-reduce, gate, in-place write
__global__ __launch_bounds__(256) void scan_passC(const float* __restrict__ delta,
                                                  float* __restrict__ u,       // overwritten with ygated
                                                  const float* __restrict__ xdbl,
                                                  const float* __restrict__ qstart,
                                                  const float* __restrict__ chunkSum,
                                                  const float* __restrict__ SuffOff,
                                                  const float* __restrict__ Dvec,
                                                  const float* __restrict__ xr) {
    int gid = blockIdx.x * 256 + threadIdx.x;
    int n = gid & 15;
    int d = (gid >> 4) & (DIN - 1);
    int c = gid >> 15;
    const float An = -(float)(n + 1);
    const float* Bbase = xdbl + DTR;
    const float* Cbase = xdbl + DTR + NST;
    int idx = (c * DIN + d) * 16 + n;
    float q = qstart[idx];
    const float soff = SuffOff[c * DIN + d];
    const float csum = chunkSum[c * DIN + d];
    const float Dd = Dvec[d];
    float s = 0.f;
    int l0 = c * CHL;
#pragma unroll 2
    for (int l = l0; l < l0 + CHL; ++l) {
        float dl = delta[l * DIN + d];
        float ul = u[l * DIN + d];
        float Bv = Bbase[l * 96 + n];
        float Cv = Cbase[l * 96 + n];
        float e = expf(An * dl);
        q = q * e + dl * ul * Bv;
        s += dl;                                  // same order as pass A -> exact at chunk end
        float suf = soff + (csum - s);
        float el = __expf(An * suf);
        float xs = q * (el / (el + 1e-12f));
        float contrib = xs * Cv;
        contrib += __shfl_xor(contrib, 1, 16);
        contrib += __shfl_xor(contrib, 2, 16);
        contrib += __shfl_xor(contrib, 4, 16);
        contrib += __shfl_xor(contrib, 8, 16);
        if (n == 0) {
            float y = contrib + ul * Dd;
            float r = xr[l * 4096 + DIN + d];      // res
            float sw = r / (1.f + expf(-r));
            u[l * DIN + d] = y * sw;               // in place; read-before-write in lockstep wave
        }
    }
}

extern "C" void kernel_launch(void* const* d_in, const int* in_sizes, int n_in,
                              void* d_out, int out_size, void* d_ws, size_t ws_size,
                              hipStream_t stream) {
    const float* x      = (const float*)d_in[0];   // (1, 2048, 1024)
    const float* W_in   = (const float*)d_in[1];   // (1024, 4096)
    const float* conv_w = (const float*)d_in[2];   // (4, 2048)
    const float* conv_b = (const float*)d_in[3];   // (2048,)
    const float* W_x    = (const float*)d_in[4];   // (2048, 96)
    const float* W_dt   = (const float*)d_in[5];   // (64, 2048)
    const float* b_dt   = (const float*)d_in[6];   // (2048,)
    const float* Dvec   = (const float*)d_in[7];   // (2048,)
    const float* W_out  = (const float*)d_in[8];   // (2048, 1024)
    float* out = (float*)d_out;                    // (1, 2048, 1024)

    float* ws = (float*)d_ws;
    float* xr    = ws;                              // 2048*4096 = 8388608
    float* xi    = ws + 8388608;                    // 2048*2048 = 4194304 (u -> ygated)
    float* xdbl  = ws + 12582912;                   // 2048*96   = 196608
    float* delta = ws + 12779520;                   // 2048*2048 = 4194304
    float* localQ= ws + 16973824;                   // 16*2048*16 = 524288
    float* Wfac  = ws + 17498112;                   // 524288
    float* qst   = ws + 18022400;                   // 524288
    float* csum  = ws + 18546688;                   // 16*2048 = 32768
    float* soff  = ws + 18579456;                   // 32768  (ends 18612224 floats = 74.4 MB)

    // 1) xr = x @ W_in    (M=2048, N=4096, K=1024)
    {
        dim3 grid(4096 / BN, L_SEQ / BM);
        gemm_f32<<<grid, 256, 0, stream>>>(x, W_in, xr, L_SEQ, 4096, DMODEL,
                                           DMODEL, 4096, 4096);
    }
    // 2) xi = swish(causal_conv(xr[:, :2048]))
    conv_swish<<<(L_SEQ * DIN) / 256, 256, 0, stream>>>(xr, conv_w, conv_b, xi);
    // 3) xdbl = xi @ W_x  (M=2048, N=96, K=2048)
    {
        dim3 grid((96 + BN - 1) / BN, L_SEQ / BM);
        gemm_f32<<<grid, 256, 0, stream>>>(xi, W_x, xdbl, L_SEQ, 96, DIN,
                                           DIN, 96, 96);
    }
    // 4) delta = softplus(xdbl[:, :64] @ W_dt + b_dt)
    delta_kernel<<<L_SEQ, 256, 0, stream>>>(xdbl, W_dt, b_dt, delta);
    // 5) chunk-parallel scan
    scan_passA<<<(DIN * NST * CCH) / 256, 256, 0, stream>>>(delta, xi, xdbl, localQ, Wfac, csum);
    scan_passB<<<(DIN * NST) / 256, 256, 0, stream>>>(localQ, Wfac, qst, csum, soff);
    scan_passC<<<(DIN * NST * CCH) / 256, 256, 0, stream>>>(delta, xi, xdbl, qst, csum, soff, Dvec, xr);
    // 6) out = ygated @ W_out (M=2048, N=1024, K=2048)
    {
        dim3 grid(DMODEL / BN, L_SEQ / BM);
        gemm_f32<<<grid, 256, 0, stream>>>(xi, W_out, out, L_SEQ, DMODEL, DIN,
                                           DIN, DMODEL, DMODEL);
    }
}

// Round 3
// 406.176 us; speedup vs baseline: 7.3388x; 3.3736x over previous
//
#include <hip/hip_runtime.h>
#include <hip/hip_bf16.h>

#define L_SEQ 2048
#define DMODEL 1024
#define DIN 2048
#define DTR 64
#define NST 16
#define CCH 16          // number of chunks
#define CHL 128         // L_SEQ / CCH

typedef unsigned short u16;
typedef __bf16 bf16x8 __attribute__((ext_vector_type(8)));
typedef float f32x4 __attribute__((ext_vector_type(4)));

__device__ inline u16 f2bf(float v) {
    __bf16 h = (__bf16)v;
    return __builtin_bit_cast(unsigned short, h);
}

// ================= bf16 MFMA GEMM: C[M,N] = A[M,K] * Bt[N,K]^T =================
// BM=128, BN=TBN (128 or 64), BK=64. 4 waves (2x2). global_load_lds staging,
// double-buffered 2-phase loop (T3 minimum recipe). Optional softplus epilogue.
template<int TBN, bool SP>
__global__ __launch_bounds__(256) void gemm_bf16(const u16* __restrict__ A,
                                                 const u16* __restrict__ Bt,
                                                 float* __restrict__ C,
                                                 const float* __restrict__ bias,
                                                 int M, int N, int K) {
    constexpr int LDSZ = (128 + TBN) * 64;         // u16 elements per buffer
    constexpr int ROUNDS = (128 + TBN) / 32;       // 32 rows staged per round
    constexpr int FN = TBN / 32;                   // B fragments per wave
    __shared__ u16 smem[2 * LDSZ];

    const int tid = threadIdx.x;
    const int lane = tid & 63;
    const int wid = tid >> 6;          // 0..3
    const int wm = wid >> 1;           // wave row 0..1
    const int wn = wid & 1;            // wave col 0..1
    const int bm = blockIdx.y * 128;
    const int bn = blockIdx.x * TBN;

    const int srow8 = lane >> 3;       // staging: row within 8-row group
    const int schunk = lane & 7;       // staging: 16B chunk within 128B row
    const int lm = lane & 15;          // fragment row/col
    const int lk = lane >> 4;          // k-group 0..3

    f32x4 acc[4][FN];
#pragma unroll
    for (int i = 0; i < 4; ++i)
#pragma unroll
        for (int j = 0; j < FN; ++j) acc[i][j] = (f32x4){0.f, 0.f, 0.f, 0.f};

    auto stage = [&](int buf, int t) {
        const int k0 = t * 64;
        u16* base = smem + buf * LDSZ;
#pragma unroll
        for (int rr = 0; rr < ROUNDS; ++rr) {
            int row = rr * 32 + wid * 8;           // wave-uniform
            int grow = row + srow8;                // per-lane global row
            const u16* src;
            if (row < 128) src = A + (size_t)(bm + grow) * K + k0 + schunk * 8;
            else           src = Bt + (size_t)(bn + grow - 128) * K + k0 + schunk * 8;
            u16* dst = base + row * 64;            // wave-uniform; HW adds lane*16B
            __builtin_amdgcn_global_load_lds(
                (const __attribute__((address_space(1))) void*)src,
                (__attribute__((address_space(3))) void*)dst, 16, 0, 0);
        }
    };

    auto compute = [&](int buf) {
        const u16* base = smem + buf * LDSZ;
#pragma unroll
        for (int kk = 0; kk < 2; ++kk) {
            bf16x8 av[4], bv[FN];
#pragma unroll
            for (int fm = 0; fm < 4; ++fm)
                av[fm] = *(const bf16x8*)(base + (wm * 64 + fm * 16 + lm) * 64 + kk * 32 + lk * 8);
#pragma unroll
            for (int fn = 0; fn < FN; ++fn)
                bv[fn] = *(const bf16x8*)(base + (128 + wn * (TBN / 2) + fn * 16 + lm) * 64 + kk * 32 + lk * 8);
#pragma unroll
            for (int fm = 0; fm < 4; ++fm)
#pragma unroll
                for (int fn = 0; fn < FN; ++fn)
                    acc[fm][fn] = __builtin_amdgcn_mfma_f32_16x16x32_bf16(av[fm], bv[fn], acc[fm][fn], 0, 0, 0);
        }
    };

    const int nt = K / 64;
    int cur = 0;
    stage(0, 0);
    __syncthreads();                    // drains vmcnt(0) before barrier
    for (int t = 0; t < nt - 1; ++t) {
        stage(cur ^ 1, t + 1);          // issue next-tile loads first
        compute(cur);
        __syncthreads();
        cur ^= 1;
    }
    compute(cur);

    // epilogue: C row = (lane>>4)*4 + j, col = lane&15 (m89-verified layout)
#pragma unroll
    for (int fm = 0; fm < 4; ++fm) {
#pragma unroll
        for (int fn = 0; fn < FN; ++fn) {
            int col = bn + wn * (TBN / 2) + fn * 16 + lm;
#pragma unroll
            for (int j = 0; j < 4; ++j) {
                int row = bm + wm * 64 + fm * 16 + lk * 4 + j;
                float v = acc[fm][fn][j];
                if (SP) {
                    v += bias[col];
                    v = (v > 20.f) ? v : log1pf(expf(v));
                }
                C[(size_t)row * N + col] = v;
            }
        }
    }
}

// ================= casts =================
__global__ __launch_bounds__(256) void cast_bf16_vec4(const float* __restrict__ in,
                                                      u16* __restrict__ out, int nvec) {
    int i = blockIdx.x * 256 + threadIdx.x;
    if (i >= nvec) return;
    float4 v = ((const float4*)in)[i];
    ushort4 o;
    o.x = f2bf(v.x); o.y = f2bf(v.y); o.z = f2bf(v.z); o.w = f2bf(v.w);
    ((ushort4*)out)[i] = o;
}

// transpose + cast: W[K][N] fp32 -> Wt[N][K] bf16. 64x64 tiles.
__global__ __launch_bounds__(256) void castT_bf16(const float* __restrict__ W,
                                                  u16* __restrict__ Wt, int K, int N) {
    __shared__ u16 tile[64][65];
    int n0 = blockIdx.x * 64, k0 = blockIdx.y * 64;
    int tn = threadIdx.x & 63, t4 = threadIdx.x >> 6;
#pragma unroll
    for (int j = 0; j < 16; ++j) {
        int k = t4 + j * 4;
        tile[tn][k] = f2bf(W[(size_t)(k0 + k) * N + n0 + tn]);
    }
    __syncthreads();
#pragma unroll
    for (int j = 0; j < 16; ++j) {
        int n = t4 + j * 4;
        Wt[(size_t)(n0 + n) * K + k0 + tn] = tile[n][tn];
    }
}

// xdbl[:, :64] -> packed bf16 [2048][64]
__global__ __launch_bounds__(256) void cast_xd(const float* __restrict__ xdbl,
                                               u16* __restrict__ xd) {
    int id = blockIdx.x * 256 + threadIdx.x;     // 0 .. 2048*64-1
    int l = id >> 6, k = id & 63;
    xd[id] = f2bf(xdbl[l * 96 + k]);
}

// ================= fp32 split-K GEMM (for xi @ W_x, N=96) =================
#define BM 64
#define BN 64
#define BK 16
__global__ __launch_bounds__(256) void gemm_f32_sk(const float* __restrict__ A,
                                                   const float* __restrict__ B,
                                                   float* __restrict__ P,
                                                   int M, int N, int K,
                                                   int lda, int ldb, int ldc, int kc) {
    __shared__ float As[BK][BM + 1];
    __shared__ float Bs[BK][BN + 1];
    const int tid = threadIdx.x;
    const int bm = blockIdx.y * BM;
    const int bn = blockIdx.x * BN;
    const int ty = tid >> 4;
    const int tx = tid & 15;
    const int kbeg = blockIdx.z * kc;
    const int kend = kbeg + kc;
    float* Cz = P + (size_t)blockIdx.z * M * ldc;

    float acc[4][4] = {};
    for (int k0 = kbeg; k0 < kend; k0 += BK) {
#pragma unroll
        for (int i = 0; i < 4; ++i) {
            int idx = tid + i * 256;
            int r = idx >> 4, c = idx & 15;
            int gr = bm + r, gc = k0 + c;
            As[c][r] = (gr < M && gc < K) ? A[gr * lda + gc] : 0.f;
        }
#pragma unroll
        for (int i = 0; i < 4; ++i) {
            int idx = tid + i * 256;
            int r = idx >> 6, c = idx & 63;
            int gr = k0 + r, gc = bn + c;
            Bs[r][c] = (gr < K && gc < N) ? B[gr * ldb + gc] : 0.f;
        }
        __syncthreads();
#pragma unroll
        for (int kk = 0; kk < BK; ++kk) {
            float a[4], b[4];
#pragma unroll
            for (int i = 0; i < 4; ++i) a[i] = As[kk][ty * 4 + i];
#pragma unroll
            for (int j = 0; j < 4; ++j) b[j] = Bs[kk][tx * 4 + j];
#pragma unroll
            for (int i = 0; i < 4; ++i)
#pragma unroll
                for (int j = 0; j < 4; ++j) acc[i][j] += a[i] * b[j];
        }
        __syncthreads();
    }
#pragma unroll
    for (int i = 0; i < 4; ++i) {
        int gr = bm + ty * 4 + i;
        if (gr >= M) continue;
#pragma unroll
        for (int j = 0; j < 4; ++j) {
            int gc = bn + tx * 4 + j;
            if (gc < N) Cz[gr * ldc + gc] = acc[i][j];
        }
    }
}

__global__ __launch_bounds__(256) void reduce_sk(const float* __restrict__ P,
                                                 float* __restrict__ xdbl) {
    int i = blockIdx.x * 256 + threadIdx.x;      // < 2048*96
    float s = 0.f;
#pragma unroll
    for (int z = 0; z < 8; ++z) s += P[z * (L_SEQ * 96) + i];
    xdbl[i] = s;
}

// ================= causal depthwise conv(4) + bias + swish =================
__global__ __launch_bounds__(256) void conv_swish(const float* __restrict__ xr,
                                                  const float* __restrict__ cw,
                                                  const float* __restrict__ cb,
                                                  float* __restrict__ xi) {
    int id = blockIdx.x * 256 + threadIdx.x;
    int l = id >> 11;
    int d = id & (DIN - 1);
    float acc = cb[d];
#pragma unroll
    for (int k = 0; k < 4; ++k) {
        int ls = l - 3 + k;
        if (ls >= 0) acc += xr[ls * 4096 + d] * cw[k * DIN + d];
    }
    xi[id] = acc / (1.f + expf(-acc));
}

// ================= chunk-parallel selective scan (fp32/fp64, unchanged) ========
__global__ __launch_bounds__(256) void scan_passA(const float* __restrict__ delta,
                                                  const float* __restrict__ u,
                                                  const float* __restrict__ xdbl,
                                                  float* __restrict__ localQ,
                                                  float* __restrict__ Wfac,
                                                  float* __restrict__ chunkSum) {
    int gid = blockIdx.x * 256 + threadIdx.x;
    int n = gid & 15;
    int d = (gid >> 4) & (DIN - 1);
    int c = gid >> 15;
    const float An = -(float)(n + 1);
    const float* Bbase = xdbl + DTR;
    float q = 0.f, s = 0.f;
    int l0 = c * CHL;
#pragma unroll 4
    for (int l = l0; l < l0 + CHL; ++l) {
        float dl = delta[l * DIN + d];
        float ul = u[l * DIN + d];
        float Bv = Bbase[l * 96 + n];
        float e = expf(An * dl);
        q = q * e + dl * ul * Bv;
        s += dl;
    }
    int idx = (c * DIN + d) * 16 + n;
    localQ[idx] = q;
    Wfac[idx] = expf(An * s);
    if (n == 0) chunkSum[c * DIN + d] = s;
}

__global__ __launch_bounds__(256) void scan_passB(const float* __restrict__ localQ,
                                                  const float* __restrict__ Wfac,
                                                  float* __restrict__ qstart,
                                                  const float* __restrict__ chunkSum,
                                                  float* __restrict__ SuffOff) {
    int gid = blockIdx.x * 256 + threadIdx.x;
    int n = gid & 15;
    int d = gid >> 4;
    float q = 0.f;
#pragma unroll
    for (int c = 0; c < CCH; ++c) {
        int idx = (c * DIN + d) * 16 + n;
        qstart[idx] = q;
        q = q * Wfac[idx] + localQ[idx];
    }
    if (n == 0) {
        double s = 0.0;
#pragma unroll
        for (int c = CCH - 1; c >= 0; --c) {
            SuffOff[c * DIN + d] = (float)s;
            s += (double)chunkSum[c * DIN + d];
        }
    }
}

__global__ __launch_bounds__(256) void scan_passC(const float* __restrict__ delta,
                                                  float* __restrict__ u,
                                                  const float* __restrict__ xdbl,
                                                  const float* __restrict__ qstart,
                                                  const float* __restrict__ chunkSum,
                                                  const float* __restrict__ SuffOff,
                                                  const float* __restrict__ Dvec,
                                                  const float* __restrict__ xr) {
    int gid = blockIdx.x * 256 + threadIdx.x;
    int n = gid & 15;
    int d = (gid >> 4) & (DIN - 1);
    int c = gid >> 15;
    const float An = -(float)(n + 1);
    const float* Bbase = xdbl + DTR;
    const float* Cbase = xdbl + DTR + NST;
    int idx = (c * DIN + d) * 16 + n;
    float q = qstart[idx];
    const float soff = SuffOff[c * DIN + d];
    const float csum = chunkSum[c * DIN + d];
    const float Dd = Dvec[d];
    float s = 0.f;
    int l0 = c * CHL;
#pragma unroll 2
    for (int l = l0; l < l0 + CHL; ++l) {
        float dl = delta[l * DIN + d];
        float ul = u[l * DIN + d];
        float Bv = Bbase[l * 96 + n];
        float Cv = Cbase[l * 96 + n];
        float e = expf(An * dl);
        q = q * e + dl * ul * Bv;
        s += dl;
        float suf = soff + (csum - s);
        float el = __expf(An * suf);
        float xs = q * (el / (el + 1e-12f));
        float contrib = xs * Cv;
        contrib += __shfl_xor(contrib, 1, 16);
        contrib += __shfl_xor(contrib, 2, 16);
        contrib += __shfl_xor(contrib, 4, 16);
        contrib += __shfl_xor(contrib, 8, 16);
        if (n == 0) {
            float y = contrib + ul * Dd;
            float r = xr[l * 4096 + DIN + d];
            float sw = r / (1.f + expf(-r));
            u[l * DIN + d] = y * sw;
        }
    }
}

extern "C" void kernel_launch(void* const* d_in, const int* in_sizes, int n_in,
                              void* d_out, int out_size, void* d_ws, size_t ws_size,
                              hipStream_t stream) {
    const float* x      = (const float*)d_in[0];   // (2048, 1024)
    const float* W_in   = (const float*)d_in[1];   // (1024, 4096)
    const float* conv_w = (const float*)d_in[2];   // (4, 2048)
    const float* conv_b = (const float*)d_in[3];   // (2048,)
    const float* W_x    = (const float*)d_in[4];   // (2048, 96)
    const float* W_dt   = (const float*)d_in[5];   // (64, 2048)
    const float* b_dt   = (const float*)d_in[6];   // (2048,)
    const float* Dvec   = (const float*)d_in[7];   // (2048,)
    const float* W_out  = (const float*)d_in[8];   // (2048, 1024)
    float* out = (float*)d_out;                    // (2048, 1024)

    float* ws = (float*)d_ws;
    float* xr    = ws;                              // 8388608 f
    float* xi    = ws + 8388608;                    // 4194304 f
    float* xdbl  = ws + 12582912;                   // 196608 f
    float* delta = ws + 12779520;                   // 4194304 f  [region D]
    float* localQ= ws + 16973824;                   // 524288 f   [region Q]
    float* Wfac  = ws + 17498112;
    float* qst   = ws + 18022400;
    float* csum  = ws + 18546688;
    float* soff  = ws + 18579456;                   // end 18612224 f = 74.4MB

    // overlays (dead-region reuse; stream-serial ordering makes these safe)
    u16* x_bf   = (u16*)(ws + 12779520);            // region D, dead before delta
    u16* WinT   = (u16*)(ws + 13828096);            // region D + 1048576 f
    float* Psk  = ws + 12779520;                    // region D (after x_bf dead)
    u16* xd_bf  = (u16*)(ws + 16973824);            // region Q (dead before passA)
    u16* WdtT   = (u16*)(ws + 17039360);            // region Q + 65536 f
    u16* y_bf   = (u16*)ws;                         // xr region (dead after passC)
    u16* WoutT  = (u16*)(ws + 2097152);             // xr region + 2097152 f

    // 1) casts for W_in GEMM
    cast_bf16_vec4<<<2048, 256, 0, stream>>>(x, x_bf, (L_SEQ * DMODEL) / 4);
    castT_bf16<<<dim3(4096 / 64, 1024 / 64), 256, 0, stream>>>(W_in, WinT, DMODEL, 4096);
    // 2) xr = x @ W_in  (M=2048, N=4096, K=1024) bf16 MFMA
    gemm_bf16<128, false><<<dim3(4096 / 128, L_SEQ / 128), 256, 0, stream>>>(
        x_bf, WinT, xr, nullptr, L_SEQ, 4096, DMODEL);
    // 3) xi = swish(causal_conv(xr[:, :2048]))
    conv_swish<<<(L_SEQ * DIN) / 256, 256, 0, stream>>>(xr, conv_w, conv_b, xi);
    // 4) xdbl = xi @ W_x  (split-K x8, fp32)
    gemm_f32_sk<<<dim3(2, L_SEQ / BM, 8), 256, 0, stream>>>(xi, W_x, Psk,
                                                            L_SEQ, 96, DIN, DIN, 96, 96, 256);
    reduce_sk<<<(L_SEQ * 96) / 256, 256, 0, stream>>>(Psk, xdbl);
    // 5) delta = softplus(xdbl[:, :64] @ W_dt + b_dt)  bf16 MFMA + epilogue
    cast_xd<<<(L_SEQ * DTR) / 256, 256, 0, stream>>>(xdbl, xd_bf);
    castT_bf16<<<dim3(2048 / 64, 64 / 64), 256, 0, stream>>>(W_dt, WdtT, DTR, DIN);
    gemm_bf16<128, true><<<dim3(DIN / 128, L_SEQ / 128), 256, 0, stream>>>(
        xd_bf, WdtT, delta, b_dt, L_SEQ, DIN, DTR);
    // 6) chunk-parallel scan (fp32)
    scan_passA<<<(DIN * NST * CCH) / 256, 256, 0, stream>>>(delta, xi, xdbl, localQ, Wfac, csum);
    scan_passB<<<(DIN * NST) / 256, 256, 0, stream>>>(localQ, Wfac, qst, csum, soff);
    scan_passC<<<(DIN * NST * CCH) / 256, 256, 0, stream>>>(delta, xi, xdbl, qst, csum, soff, Dvec, xr);
    // 7) out = ygated @ W_out  (M=2048, N=1024, K=2048) bf16 MFMA, BN=64
    cast_bf16_vec4<<<4096, 256, 0, stream>>>(xi, y_bf, (L_SEQ * DIN) / 4);
    castT_bf16<<<dim3(1024 / 64, 2048 / 64), 256, 0, stream>>>(W_out, WoutT, DIN, DMODEL);
    gemm_bf16<64, false><<<dim3(DMODEL / 64, L_SEQ / 128), 256, 0, stream>>>(
        y_bf, WoutT, out, nullptr, L_SEQ, DMODEL, DIN);
}

// Round 4
// 296.051 us; speedup vs baseline: 10.0687x; 1.3720x over previous
//
#include <hip/hip_runtime.h>
#include <hip/hip_bf16.h>

#define L_SEQ 2048
#define DMODEL 1024
#define DIN 2048
#define DTR 64
#define NST 16
#define CCH 16          // number of chunks
#define CHL 128         // L_SEQ / CCH

typedef unsigned short u16;
typedef __bf16 bf16x8 __attribute__((ext_vector_type(8)));
typedef float f32x4 __attribute__((ext_vector_type(4)));

__device__ inline u16 f2bf(float v) {
    __bf16 h = (__bf16)v;
    return __builtin_bit_cast(unsigned short, h);
}
__device__ inline float rcpf(float x) { return __builtin_amdgcn_rcpf(x); }
__device__ inline float swishf(float v) { return v * rcpf(1.f + __expf(-v)); }
__device__ inline float softplusf(float v) {
    return (v > 20.f) ? v : __logf(1.f + __expf(v));
}

// ================= bf16 MFMA GEMM: C[M,N] = A[M,K] * Bt[N,K]^T =================
// BM=128, BN=TBN (128 or 64), BK=64. 4 waves (2x2). global_load_lds staging,
// double-buffered 2-phase loop. Optional softplus epilogue.
template<int TBN, bool SP>
__global__ __launch_bounds__(256) void gemm_bf16(const u16* __restrict__ A,
                                                 const u16* __restrict__ Bt,
                                                 float* __restrict__ C,
                                                 const float* __restrict__ bias,
                                                 int M, int N, int K) {
    constexpr int LDSZ = (128 + TBN) * 64;         // u16 elements per buffer
    constexpr int ROUNDS = (128 + TBN) / 32;       // 32 rows staged per round
    constexpr int FN = TBN / 32;                   // B fragments per wave
    __shared__ u16 smem[2 * LDSZ];

    const int tid = threadIdx.x;
    const int lane = tid & 63;
    const int wid = tid >> 6;          // 0..3
    const int wm = wid >> 1;           // wave row 0..1
    const int wn = wid & 1;            // wave col 0..1
    const int bm = blockIdx.y * 128;
    const int bn = blockIdx.x * TBN;

    const int srow8 = lane >> 3;       // staging: row within 8-row group
    const int schunk = lane & 7;       // staging: 16B chunk within 128B row
    const int lm = lane & 15;          // fragment row/col
    const int lk = lane >> 4;          // k-group 0..3

    f32x4 acc[4][FN];
#pragma unroll
    for (int i = 0; i < 4; ++i)
#pragma unroll
        for (int j = 0; j < FN; ++j) acc[i][j] = (f32x4){0.f, 0.f, 0.f, 0.f};

    auto stage = [&](int buf, int t) {
        const int k0 = t * 64;
        u16* base = smem + buf * LDSZ;
#pragma unroll
        for (int rr = 0; rr < ROUNDS; ++rr) {
            int row = rr * 32 + wid * 8;           // wave-uniform
            int grow = row + srow8;                // per-lane global row
            const u16* src;
            if (row < 128) src = A + (size_t)(bm + grow) * K + k0 + schunk * 8;
            else           src = Bt + (size_t)(bn + grow - 128) * K + k0 + schunk * 8;
            u16* dst = base + row * 64;            // wave-uniform; HW adds lane*16B
            __builtin_amdgcn_global_load_lds(
                (const __attribute__((address_space(1))) void*)src,
                (__attribute__((address_space(3))) void*)dst, 16, 0, 0);
        }
    };

    auto compute = [&](int buf) {
        const u16* base = smem + buf * LDSZ;
#pragma unroll
        for (int kk = 0; kk < 2; ++kk) {
            bf16x8 av[4], bv[FN];
#pragma unroll
            for (int fm = 0; fm < 4; ++fm)
                av[fm] = *(const bf16x8*)(base + (wm * 64 + fm * 16 + lm) * 64 + kk * 32 + lk * 8);
#pragma unroll
            for (int fn = 0; fn < FN; ++fn)
                bv[fn] = *(const bf16x8*)(base + (128 + wn * (TBN / 2) + fn * 16 + lm) * 64 + kk * 32 + lk * 8);
#pragma unroll
            for (int fm = 0; fm < 4; ++fm)
#pragma unroll
                for (int fn = 0; fn < FN; ++fn)
                    acc[fm][fn] = __builtin_amdgcn_mfma_f32_16x16x32_bf16(av[fm], bv[fn], acc[fm][fn], 0, 0, 0);
        }
    };

    const int nt = K / 64;
    int cur = 0;
    stage(0, 0);
    __syncthreads();                    // drains vmcnt(0) before barrier
    for (int t = 0; t < nt - 1; ++t) {
        stage(cur ^ 1, t + 1);          // issue next-tile loads first
        compute(cur);
        __syncthreads();
        cur ^= 1;
    }
    compute(cur);

    // epilogue: C row = (lane>>4)*4 + j, col = lane&15
#pragma unroll
    for (int fm = 0; fm < 4; ++fm) {
#pragma unroll
        for (int fn = 0; fn < FN; ++fn) {
            int col = bn + wn * (TBN / 2) + fn * 16 + lm;
#pragma unroll
            for (int j = 0; j < 4; ++j) {
                int row = bm + wm * 64 + fm * 16 + lk * 4 + j;
                float v = acc[fm][fn][j];
                if (SP) {
                    v += bias[col];
                    v = softplusf(v);
                }
                C[(size_t)row * N + col] = v;
            }
        }
    }
}

// ================= casts =================
__global__ __launch_bounds__(256) void cast_bf16_vec4(const float* __restrict__ in,
                                                      u16* __restrict__ out, int nvec) {
    int i = blockIdx.x * 256 + threadIdx.x;
    if (i >= nvec) return;
    float4 v = ((const float4*)in)[i];
    ushort4 o;
    o.x = f2bf(v.x); o.y = f2bf(v.y); o.z = f2bf(v.z); o.w = f2bf(v.w);
    ((ushort4*)out)[i] = o;
}

// transpose + cast: W[K][N] fp32 -> Wt[N][K] bf16. 64x64 tiles.
__global__ __launch_bounds__(256) void castT_bf16(const float* __restrict__ W,
                                                  u16* __restrict__ Wt, int K, int N) {
    __shared__ u16 tile[64][65];
    int n0 = blockIdx.x * 64, k0 = blockIdx.y * 64;
    int tn = threadIdx.x & 63, t4 = threadIdx.x >> 6;
#pragma unroll
    for (int j = 0; j < 16; ++j) {
        int k = t4 + j * 4;
        tile[tn][k] = f2bf(W[(size_t)(k0 + k) * N + n0 + tn]);
    }
    __syncthreads();
#pragma unroll
    for (int j = 0; j < 16; ++j) {
        int n = t4 + j * 4;
        Wt[(size_t)(n0 + n) * K + k0 + tn] = tile[n][tn];
    }
}

// xdbl[:, :64] -> packed bf16 [2048][64]
__global__ __launch_bounds__(256) void cast_xd(const float* __restrict__ xdbl,
                                               u16* __restrict__ xd) {
    int id = blockIdx.x * 256 + threadIdx.x;     // 0 .. 2048*64-1
    int l = id >> 6, k = id & 63;
    xd[id] = f2bf(xdbl[l * 96 + k]);
}

// ================= fp32 split-K GEMM (for xi @ W_x, N=96) =================
#define BM 64
#define BN 64
#define BK 16
__global__ __launch_bounds__(256) void gemm_f32_sk(const float* __restrict__ A,
                                                   const float* __restrict__ B,
                                                   float* __restrict__ P,
                                                   int M, int N, int K,
                                                   int lda, int ldb, int ldc, int kc) {
    __shared__ float As[BK][BM + 1];
    __shared__ float Bs[BK][BN + 1];
    const int tid = threadIdx.x;
    const int bm = blockIdx.y * BM;
    const int bn = blockIdx.x * BN;
    const int ty = tid >> 4;
    const int tx = tid & 15;
    const int kbeg = blockIdx.z * kc;
    const int kend = kbeg + kc;
    float* Cz = P + (size_t)blockIdx.z * M * ldc;

    float acc[4][4] = {};
    for (int k0 = kbeg; k0 < kend; k0 += BK) {
#pragma unroll
        for (int i = 0; i < 4; ++i) {
            int idx = tid + i * 256;
            int r = idx >> 4, c = idx & 15;
            int gr = bm + r, gc = k0 + c;
            As[c][r] = (gr < M && gc < K) ? A[gr * lda + gc] : 0.f;
        }
#pragma unroll
        for (int i = 0; i < 4; ++i) {
            int idx = tid + i * 256;
            int r = idx >> 6, c = idx & 63;
            int gr = k0 + r, gc = bn + c;
            Bs[r][c] = (gr < K && gc < N) ? B[gr * ldb + gc] : 0.f;
        }
        __syncthreads();
#pragma unroll
        for (int kk = 0; kk < BK; ++kk) {
            float a[4], b[4];
#pragma unroll
            for (int i = 0; i < 4; ++i) a[i] = As[kk][ty * 4 + i];
#pragma unroll
            for (int j = 0; j < 4; ++j) b[j] = Bs[kk][tx * 4 + j];
#pragma unroll
            for (int i = 0; i < 4; ++i)
#pragma unroll
                for (int j = 0; j < 4; ++j) acc[i][j] += a[i] * b[j];
        }
        __syncthreads();
    }
#pragma unroll
    for (int i = 0; i < 4; ++i) {
        int gr = bm + ty * 4 + i;
        if (gr >= M) continue;
#pragma unroll
        for (int j = 0; j < 4; ++j) {
            int gc = bn + tx * 4 + j;
            if (gc < N) Cz[gr * ldc + gc] = acc[i][j];
        }
    }
}

__global__ __launch_bounds__(256) void reduce_sk(const float* __restrict__ P,
                                                 float* __restrict__ xdbl) {
    int i = blockIdx.x * 256 + threadIdx.x;      // < 2048*96
    float s = 0.f;
#pragma unroll
    for (int z = 0; z < 8; ++z) s += P[z * (L_SEQ * 96) + i];
    xdbl[i] = s;
}

// ================= causal depthwise conv(4) + bias + swish =================
__global__ __launch_bounds__(256) void conv_swish(const float* __restrict__ xr,
                                                  const float* __restrict__ cw,
                                                  const float* __restrict__ cb,
                                                  float* __restrict__ xi) {
    int id = blockIdx.x * 256 + threadIdx.x;
    int l = id >> 11;
    int d = id & (DIN - 1);
    float acc = cb[d];
#pragma unroll
    for (int k = 0; k < 4; ++k) {
        int ls = l - 3 + k;
        if (ls >= 0) acc += xr[ls * 4096 + d] * cw[k * DIN + d];
    }
    xi[id] = swishf(acc);
}

// ================= chunk-parallel selective scan ========
// q_l = q_{l-1}*exp(An*d_l) + d_l*u_l*B_l;  xs_l = q_l * el/(el+1e-12),
// el = exp(An * suffix_l).
__global__ __launch_bounds__(256) void scan_passA(const float* __restrict__ delta,
                                                  const float* __restrict__ u,
                                                  const float* __restrict__ xdbl,
                                                  float* __restrict__ localQ,
                                                  float* __restrict__ Wfac,
                                                  float* __restrict__ chunkSum) {
    int gid = blockIdx.x * 256 + threadIdx.x;
    int n = gid & 15;
    int d = (gid >> 4) & (DIN - 1);
    int c = gid >> 15;
    const float An = -(float)(n + 1);
    const float* Bbase = xdbl + DTR;
    float q = 0.f, s = 0.f;
    int l0 = c * CHL;
#pragma unroll 4
    for (int l = l0; l < l0 + CHL; ++l) {
        float dl = delta[l * DIN + d];
        float ul = u[l * DIN + d];
        float Bv = Bbase[l * 96 + n];
        float e = __expf(An * dl);
        q = q * e + dl * ul * Bv;
        s += dl;
    }
    int idx = (c * DIN + d) * 16 + n;
    localQ[idx] = q;
    Wfac[idx] = __expf(An * s);
    if (n == 0) chunkSum[c * DIN + d] = s;
}

__global__ __launch_bounds__(256) void scan_passB(const float* __restrict__ localQ,
                                                  const float* __restrict__ Wfac,
                                                  float* __restrict__ qstart,
                                                  const float* __restrict__ chunkSum,
                                                  float* __restrict__ SuffOff) {
    int gid = blockIdx.x * 256 + threadIdx.x;
    int n = gid & 15;
    int d = gid >> 4;
    float q = 0.f;
#pragma unroll
    for (int c = 0; c < CCH; ++c) {
        int idx = (c * DIN + d) * 16 + n;
        qstart[idx] = q;
        q = q * Wfac[idx] + localQ[idx];
    }
    if (n == 0) {
        double s = 0.0;
#pragma unroll
        for (int c = CCH - 1; c >= 0; --c) {
            SuffOff[c * DIN + d] = (float)s;
            s += (double)chunkSum[c * DIN + d];
        }
    }
}

__global__ __launch_bounds__(256) void scan_passC(const float* __restrict__ delta,
                                                  float* __restrict__ u,
                                                  const float* __restrict__ xdbl,
                                                  const float* __restrict__ qstart,
                                                  const float* __restrict__ chunkSum,
                                                  const float* __restrict__ SuffOff,
                                                  const float* __restrict__ Dvec,
                                                  const float* __restrict__ xr) {
    int gid = blockIdx.x * 256 + threadIdx.x;
    int n = gid & 15;
    int d = (gid >> 4) & (DIN - 1);
    int c = gid >> 15;
    const float An = -(float)(n + 1);
    const float* Bbase = xdbl + DTR;
    const float* Cbase = xdbl + DTR + NST;
    int idx = (c * DIN + d) * 16 + n;
    float q = qstart[idx];
    const float send = SuffOff[c * DIN + d] + chunkSum[c * DIN + d];
    const float Dd = Dvec[d];
    float s = 0.f;
    int l0 = c * CHL;
#pragma unroll 4
    for (int l = l0; l < l0 + CHL; ++l) {
        float dl = delta[l * DIN + d];
        float ul = u[l * DIN + d];
        float Bv = Bbase[l * 96 + n];
        float Cv = Cbase[l * 96 + n];
        float e = __expf(An * dl);
        q = q * e + dl * ul * Bv;
        s += dl;                                  // same order as pass A
        float el = __expf(An * (send - s));
        float xs = q * el * rcpf(el + 1e-12f);
        float contrib = xs * Cv;
        contrib += __shfl_xor(contrib, 1, 16);
        contrib += __shfl_xor(contrib, 2, 16);
        contrib += __shfl_xor(contrib, 4, 16);
        contrib += __shfl_xor(contrib, 8, 16);
        if (n == 0) {
            float y = contrib + ul * Dd;
            float r = xr[l * 4096 + DIN + d];
            u[l * DIN + d] = y * swishf(r);
        }
    }
}

extern "C" void kernel_launch(void* const* d_in, const int* in_sizes, int n_in,
                              void* d_out, int out_size, void* d_ws, size_t ws_size,
                              hipStream_t stream) {
    const float* x      = (const float*)d_in[0];   // (2048, 1024)
    const float* W_in   = (const float*)d_in[1];   // (1024, 4096)
    const float* conv_w = (const float*)d_in[2];   // (4, 2048)
    const float* conv_b = (const float*)d_in[3];   // (2048,)
    const float* W_x    = (const float*)d_in[4];   // (2048, 96)
    const float* W_dt   = (const float*)d_in[5];   // (64, 2048)
    const float* b_dt   = (const float*)d_in[6];   // (2048,)
    const float* Dvec   = (const float*)d_in[7];   // (2048,)
    const float* W_out  = (const float*)d_in[8];   // (2048, 1024)
    float* out = (float*)d_out;                    // (2048, 1024)

    float* ws = (float*)d_ws;
    float* xr    = ws;                              // 8388608 f
    float* xi    = ws + 8388608;                    // 4194304 f
    float* xdbl  = ws + 12582912;                   // 196608 f
    float* delta = ws + 12779520;                   // 4194304 f  [region D]
    float* localQ= ws + 16973824;                   // 524288 f   [region Q]
    float* Wfac  = ws + 17498112;
    float* qst   = ws + 18022400;
    float* csum  = ws + 18546688;
    float* soff  = ws + 18579456;                   // end 18612224 f = 74.4MB

    // overlays (dead-region reuse; stream-serial ordering makes these safe)
    u16* x_bf   = (u16*)(ws + 12779520);            // region D, dead before delta
    u16* WinT   = (u16*)(ws + 13828096);            // region D + 1048576 f
    float* Psk  = ws + 12779520;                    // region D (after x_bf dead)
    u16* xd_bf  = (u16*)(ws + 16973824);            // region Q (dead before passA)
    u16* WdtT   = (u16*)(ws + 17039360);            // region Q + 65536 f
    u16* y_bf   = (u16*)ws;                         // xr region (dead after passC)
    u16* WoutT  = (u16*)(ws + 2097152);             // xr region + 2097152 f

    // 1) casts for W_in GEMM
    cast_bf16_vec4<<<2048, 256, 0, stream>>>(x, x_bf, (L_SEQ * DMODEL) / 4);
    castT_bf16<<<dim3(4096 / 64, 1024 / 64), 256, 0, stream>>>(W_in, WinT, DMODEL, 4096);
    // 2) xr = x @ W_in  (M=2048, N=4096, K=1024) bf16 MFMA
    gemm_bf16<128, false><<<dim3(4096 / 128, L_SEQ / 128), 256, 0, stream>>>(
        x_bf, WinT, xr, nullptr, L_SEQ, 4096, DMODEL);
    // 3) xi = swish(causal_conv(xr[:, :2048]))
    conv_swish<<<(L_SEQ * DIN) / 256, 256, 0, stream>>>(xr, conv_w, conv_b, xi);
    // 4) xdbl = xi @ W_x  (split-K x8, fp32)
    gemm_f32_sk<<<dim3(2, L_SEQ / BM, 8), 256, 0, stream>>>(xi, W_x, Psk,
                                                            L_SEQ, 96, DIN, DIN, 96, 96, 256);
    reduce_sk<<<(L_SEQ * 96) / 256, 256, 0, stream>>>(Psk, xdbl);
    // 5) delta = softplus(xdbl[:, :64] @ W_dt + b_dt)  bf16 MFMA + epilogue
    cast_xd<<<(L_SEQ * DTR) / 256, 256, 0, stream>>>(xdbl, xd_bf);
    castT_bf16<<<dim3(2048 / 64, 64 / 64), 256, 0, stream>>>(W_dt, WdtT, DTR, DIN);
    gemm_bf16<128, true><<<dim3(DIN / 128, L_SEQ / 128), 256, 0, stream>>>(
        xd_bf, WdtT, delta, b_dt, L_SEQ, DIN, DTR);
    // 6) chunk-parallel scan (fp32)
    scan_passA<<<(DIN * NST * CCH) / 256, 256, 0, stream>>>(delta, xi, xdbl, localQ, Wfac, csum);
    scan_passB<<<(DIN * NST) / 256, 256, 0, stream>>>(localQ, Wfac, qst, csum, soff);
    scan_passC<<<(DIN * NST * CCH) / 256, 256, 0, stream>>>(delta, xi, xdbl, qst, csum, soff, Dvec, xr);
    // 7) out = ygated @ W_out  (M=2048, N=1024, K=2048) bf16 MFMA, BN=64
    cast_bf16_vec4<<<4096, 256, 0, stream>>>(xi, y_bf, (L_SEQ * DIN) / 4);
    castT_bf16<<<dim3(1024 / 64, 2048 / 64), 256, 0, stream>>>(W_out, WoutT, DIN, DMODEL);
    gemm_bf16<64, false><<<dim3(DMODEL / 64, L_SEQ / 128), 256, 0, stream>>>(
        y_bf, WoutT, out, nullptr, L_SEQ, DMODEL, DIN);
}

// Round 5
// 220.183 us; speedup vs baseline: 13.5380x; 1.3446x over previous
//
#include <hip/hip_runtime.h>
#include <hip/hip_bf16.h>

#define L_SEQ 2048
#define DMODEL 1024
#define DIN 2048
#define DTR 64
#define NST 16
#define CCH 128         // number of chunks
#define CHL 16          // L_SEQ / CCH

typedef unsigned short u16;
typedef __bf16 bf16x8 __attribute__((ext_vector_type(8)));
typedef float f32x4 __attribute__((ext_vector_type(4)));

__device__ inline u16 f2bf(float v) {
    __bf16 h = (__bf16)v;
    return __builtin_bit_cast(unsigned short, h);
}
__device__ inline float rcpf(float x) { return __builtin_amdgcn_rcpf(x); }
__device__ inline float swishf(float v) { return v * rcpf(1.f + __expf(-v)); }
__device__ inline float softplusf(float v) {
    return (v > 20.f) ? v : __logf(1.f + __expf(v));
}

// p[n] = v^(n+1), depth-4 multiply tree (replaces 16 v_exp with 1 exp + 15 mul)
__device__ inline void powers16(float v, float* p) {
    p[0] = v;
    p[1] = v * v;
    p[2] = p[1] * v;
    p[3] = p[1] * p[1];
    p[4] = p[3] * p[0];  p[5] = p[3] * p[1];  p[6] = p[3] * p[2];  p[7] = p[3] * p[3];
    p[8] = p[7] * p[0];  p[9] = p[7] * p[1];  p[10] = p[7] * p[2]; p[11] = p[7] * p[3];
    p[12] = p[7] * p[4]; p[13] = p[7] * p[5]; p[14] = p[7] * p[6]; p[15] = p[7] * p[7];
}

// localQ lives in the DEAD half-columns of xr: linear idx -> ws[row*4096 + col],
// col = idx & 2047 (xr cols 0..2047 are dead after conv_swish; res = cols 2048+).
__device__ inline float* lqp(float* wsf, int idx) {
    return wsf + ((idx >> 11) << 12) + (idx & 2047);
}

// ================= bf16 MFMA GEMM: C[M,N] = A[M,K] * Bt[N,K]^T =================
template<int TBN, bool SP>
__global__ __launch_bounds__(256) void gemm_bf16(const u16* __restrict__ A,
                                                 const u16* __restrict__ Bt,
                                                 float* __restrict__ C,
                                                 const float* __restrict__ bias,
                                                 int M, int N, int K) {
    constexpr int LDSZ = (128 + TBN) * 64;
    constexpr int ROUNDS = (128 + TBN) / 32;
    constexpr int FN = TBN / 32;
    __shared__ u16 smem[2 * LDSZ];

    const int tid = threadIdx.x;
    const int lane = tid & 63;
    const int wid = tid >> 6;
    const int wm = wid >> 1;
    const int wn = wid & 1;
    const int bm = blockIdx.y * 128;
    const int bn = blockIdx.x * TBN;

    const int srow8 = lane >> 3;
    const int schunk = lane & 7;
    const int lm = lane & 15;
    const int lk = lane >> 4;

    f32x4 acc[4][FN];
#pragma unroll
    for (int i = 0; i < 4; ++i)
#pragma unroll
        for (int j = 0; j < FN; ++j) acc[i][j] = (f32x4){0.f, 0.f, 0.f, 0.f};

    auto stage = [&](int buf, int t) {
        const int k0 = t * 64;
        u16* base = smem + buf * LDSZ;
#pragma unroll
        for (int rr = 0; rr < ROUNDS; ++rr) {
            int row = rr * 32 + wid * 8;
            int grow = row + srow8;
            const u16* src;
            if (row < 128) src = A + (size_t)(bm + grow) * K + k0 + schunk * 8;
            else           src = Bt + (size_t)(bn + grow - 128) * K + k0 + schunk * 8;
            u16* dst = base + row * 64;
            __builtin_amdgcn_global_load_lds(
                (const __attribute__((address_space(1))) void*)src,
                (__attribute__((address_space(3))) void*)dst, 16, 0, 0);
        }
    };

    auto compute = [&](int buf) {
        const u16* base = smem + buf * LDSZ;
#pragma unroll
        for (int kk = 0; kk < 2; ++kk) {
            bf16x8 av[4], bv[FN];
#pragma unroll
            for (int fm = 0; fm < 4; ++fm)
                av[fm] = *(const bf16x8*)(base + (wm * 64 + fm * 16 + lm) * 64 + kk * 32 + lk * 8);
#pragma unroll
            for (int fn = 0; fn < FN; ++fn)
                bv[fn] = *(const bf16x8*)(base + (128 + wn * (TBN / 2) + fn * 16 + lm) * 64 + kk * 32 + lk * 8);
#pragma unroll
            for (int fm = 0; fm < 4; ++fm)
#pragma unroll
                for (int fn = 0; fn < FN; ++fn)
                    acc[fm][fn] = __builtin_amdgcn_mfma_f32_16x16x32_bf16(av[fm], bv[fn], acc[fm][fn], 0, 0, 0);
        }
    };

    const int nt = K / 64;
    int cur = 0;
    stage(0, 0);
    __syncthreads();
    for (int t = 0; t < nt - 1; ++t) {
        stage(cur ^ 1, t + 1);
        compute(cur);
        __syncthreads();
        cur ^= 1;
    }
    compute(cur);

#pragma unroll
    for (int fm = 0; fm < 4; ++fm) {
#pragma unroll
        for (int fn = 0; fn < FN; ++fn) {
            int col = bn + wn * (TBN / 2) + fn * 16 + lm;
#pragma unroll
            for (int j = 0; j < 4; ++j) {
                int row = bm + wm * 64 + fm * 16 + lk * 4 + j;
                float v = acc[fm][fn][j];
                if (SP) {
                    v += bias[col];
                    v = softplusf(v);
                }
                C[(size_t)row * N + col] = v;
            }
        }
    }
}

// ================= casts =================
__global__ __launch_bounds__(256) void cast_bf16_vec4(const float* __restrict__ in,
                                                      u16* __restrict__ out, int nvec) {
    int i = blockIdx.x * 256 + threadIdx.x;
    if (i >= nvec) return;
    float4 v = ((const float4*)in)[i];
    ushort4 o;
    o.x = f2bf(v.x); o.y = f2bf(v.y); o.z = f2bf(v.z); o.w = f2bf(v.w);
    ((ushort4*)out)[i] = o;
}

__global__ __launch_bounds__(256) void castT_bf16(const float* __restrict__ W,
                                                  u16* __restrict__ Wt, int K, int N) {
    __shared__ u16 tile[64][65];
    int n0 = blockIdx.x * 64, k0 = blockIdx.y * 64;
    int tn = threadIdx.x & 63, t4 = threadIdx.x >> 6;
#pragma unroll
    for (int j = 0; j < 16; ++j) {
        int k = t4 + j * 4;
        tile[tn][k] = f2bf(W[(size_t)(k0 + k) * N + n0 + tn]);
    }
    __syncthreads();
#pragma unroll
    for (int j = 0; j < 16; ++j) {
        int n = t4 + j * 4;
        Wt[(size_t)(n0 + n) * K + k0 + tn] = tile[n][tn];
    }
}

__global__ __launch_bounds__(256) void cast_xd(const float* __restrict__ xdbl,
                                               u16* __restrict__ xd) {
    int id = blockIdx.x * 256 + threadIdx.x;
    int l = id >> 6, k = id & 63;
    xd[id] = f2bf(xdbl[l * 96 + k]);
}

// ================= fp32 split-K GEMM (for xi @ W_x, N=96) =================
#define BM 64
#define BN 64
#define BK 16
__global__ __launch_bounds__(256) void gemm_f32_sk(const float* __restrict__ A,
                                                   const float* __restrict__ B,
                                                   float* __restrict__ P,
                                                   int M, int N, int K,
                                                   int lda, int ldb, int ldc, int kc) {
    __shared__ float As[BK][BM + 1];
    __shared__ float Bs[BK][BN + 1];
    const int tid = threadIdx.x;
    const int bm = blockIdx.y * BM;
    const int bn = blockIdx.x * BN;
    const int ty = tid >> 4;
    const int tx = tid & 15;
    const int kbeg = blockIdx.z * kc;
    const int kend = kbeg + kc;
    float* Cz = P + (size_t)blockIdx.z * M * ldc;

    float acc[4][4] = {};
    for (int k0 = kbeg; k0 < kend; k0 += BK) {
#pragma unroll
        for (int i = 0; i < 4; ++i) {
            int idx = tid + i * 256;
            int r = idx >> 4, c = idx & 15;
            int gr = bm + r, gc = k0 + c;
            As[c][r] = (gr < M && gc < K) ? A[gr * lda + gc] : 0.f;
        }
#pragma unroll
        for (int i = 0; i < 4; ++i) {
            int idx = tid + i * 256;
            int r = idx >> 6, c = idx & 63;
            int gr = k0 + r, gc = bn + c;
            Bs[r][c] = (gr < K && gc < N) ? B[gr * ldb + gc] : 0.f;
        }
        __syncthreads();
#pragma unroll
        for (int kk = 0; kk < BK; ++kk) {
            float a[4], b[4];
#pragma unroll
            for (int i = 0; i < 4; ++i) a[i] = As[kk][ty * 4 + i];
#pragma unroll
            for (int j = 0; j < 4; ++j) b[j] = Bs[kk][tx * 4 + j];
#pragma unroll
            for (int i = 0; i < 4; ++i)
#pragma unroll
                for (int j = 0; j < 4; ++j) acc[i][j] += a[i] * b[j];
        }
        __syncthreads();
    }
#pragma unroll
    for (int i = 0; i < 4; ++i) {
        int gr = bm + ty * 4 + i;
        if (gr >= M) continue;
#pragma unroll
        for (int j = 0; j < 4; ++j) {
            int gc = bn + tx * 4 + j;
            if (gc < N) Cz[gr * ldc + gc] = acc[i][j];
        }
    }
}

__global__ __launch_bounds__(256) void reduce_sk(const float* __restrict__ P,
                                                 float* __restrict__ xdbl) {
    int i = blockIdx.x * 256 + threadIdx.x;
    float s = 0.f;
#pragma unroll
    for (int z = 0; z < 8; ++z) s += P[z * (L_SEQ * 96) + i];
    xdbl[i] = s;
}

// ================= causal depthwise conv(4) + bias + swish =================
__global__ __launch_bounds__(256) void conv_swish(const float* __restrict__ xr,
                                                  const float* __restrict__ cw,
                                                  const float* __restrict__ cb,
                                                  float* __restrict__ xi) {
    int id = blockIdx.x * 256 + threadIdx.x;
    int l = id >> 11;
    int d = id & (DIN - 1);
    float acc = cb[d];
#pragma unroll
    for (int k = 0; k < 4; ++k) {
        int ls = l - 3 + k;
        if (ls >= 0) acc += xr[ls * 4096 + d] * cw[k * DIN + d];
    }
    xi[id] = swishf(acc);
}

// ================= chunk-parallel selective scan, n-fused ========
// Thread = (d, chunk). 16 n-states in registers; e_n/el_n via power trees.
// q_l = q*v^(n+1) + d*u*B;  xs = q*g, g = el/(el+1e-12), el = w^(n+1),
// w = exp(-suf). 3-regime g: suf<0.8 -> g=1; suf>40 -> g=el*1e12; else exact.

__global__ __launch_bounds__(256) void scanA(const float* __restrict__ delta,
                                             const float* __restrict__ u,
                                             const float* __restrict__ xdbl,
                                             float* __restrict__ wsf,
                                             float* __restrict__ csum) {
    __shared__ float sh[CHL][16];
    const int tid = threadIdx.x;
    const int c = blockIdx.y;
    const int d = blockIdx.x * 256 + tid;
    const int l0 = c * CHL;
    {
        int l = tid >> 4, j = tid & 15;
        sh[l][j] = xdbl[(l0 + l) * 96 + DTR + j];
    }
    __syncthreads();
    float q[16];
#pragma unroll
    for (int n = 0; n < 16; ++n) q[n] = 0.f;
    float s = 0.f;
#pragma unroll 2
    for (int l = 0; l < CHL; ++l) {
        float dl = delta[(l0 + l) * DIN + d];
        float ul = u[(l0 + l) * DIN + d];
        float bb[16];
        const float4* shv = (const float4*)&sh[l][0];
        *(float4*)&bb[0] = shv[0];  *(float4*)&bb[4] = shv[1];
        *(float4*)&bb[8] = shv[2];  *(float4*)&bb[12] = shv[3];
        float v = __expf(-dl);
        float p[16];
        powers16(v, p);
        float dlul = dl * ul;
#pragma unroll
        for (int n = 0; n < 16; ++n) q[n] = q[n] * p[n] + dlul * bb[n];
        s += dl;
    }
    float* dst = lqp(wsf, (c * DIN + d) * 16);
    *(float4*)(dst + 0)  = make_float4(q[0], q[1], q[2], q[3]);
    *(float4*)(dst + 4)  = make_float4(q[4], q[5], q[6], q[7]);
    *(float4*)(dst + 8)  = make_float4(q[8], q[9], q[10], q[11]);
    *(float4*)(dst + 12) = make_float4(q[12], q[13], q[14], q[15]);
    csum[c * DIN + d] = s;
}

// cross-chunk combine: qstart written in-place over localQ; send[c][d] = suffix
// delta-sum including chunk c (double accumulation).
__global__ __launch_bounds__(256) void scanB(float* __restrict__ wsf,
                                             const float* __restrict__ csum,
                                             float* __restrict__ send) {
    int gid = blockIdx.x * 256 + threadIdx.x;   // 0 .. DIN*16-1
    int n = gid & 15;
    int d = gid >> 4;
    const float An = -(float)(n + 1);
    float q = 0.f;
#pragma unroll 4
    for (int c = 0; c < CCH; ++c) {
        float cs = csum[c * DIN + d];
        float w = __expf(An * cs);
        float* lq = lqp(wsf, (c * DIN + d) * 16 + n);
        float lv = *lq;
        *lq = q;                 // qstart for chunk c
        q = q * w + lv;
    }
    if (n == 0) {
        double ssum = 0.0;
        for (int c = CCH - 1; c >= 0; --c) {
            ssum += (double)csum[c * DIN + d];
            send[c * DIN + d] = (float)ssum;
        }
    }
}

__global__ __launch_bounds__(256) void scanC(const float* __restrict__ delta,
                                             float* __restrict__ u,
                                             const float* __restrict__ xdbl,
                                             float* __restrict__ wsf,
                                             const float* __restrict__ send,
                                             const float* __restrict__ Dvec,
                                             const float* __restrict__ xr) {
    __shared__ float sh[CHL][32];
    const int tid = threadIdx.x;
    const int c = blockIdx.y;
    const int d = blockIdx.x * 256 + tid;
    const int l0 = c * CHL;
#pragma unroll
    for (int k = 0; k < 2; ++k) {
        int idx = tid + k * 256;
        int l = idx >> 5, j = idx & 31;
        sh[l][j] = xdbl[(l0 + l) * 96 + DTR + j];
    }
    __syncthreads();
    float q[16];
    {
        const float* src = lqp(wsf, (c * DIN + d) * 16);
        float4 t0 = *(const float4*)(src + 0);
        float4 t1 = *(const float4*)(src + 4);
        float4 t2 = *(const float4*)(src + 8);
        float4 t3 = *(const float4*)(src + 12);
        q[0] = t0.x; q[1] = t0.y; q[2] = t0.z; q[3] = t0.w;
        q[4] = t1.x; q[5] = t1.y; q[6] = t1.z; q[7] = t1.w;
        q[8] = t2.x; q[9] = t2.y; q[10] = t2.z; q[11] = t2.w;
        q[12] = t3.x; q[13] = t3.y; q[14] = t3.z; q[15] = t3.w;
    }
    const float send_cd = send[c * DIN + d];
    const float Dd = Dvec[d];
    float s = 0.f;
#pragma unroll 2
    for (int l = 0; l < CHL; ++l) {
        float dl = delta[(l0 + l) * DIN + d];
        float ul = u[(l0 + l) * DIN + d];
        float bb[32];
        const float4* shv = (const float4*)&sh[l][0];
        *(float4*)&bb[0]  = shv[0]; *(float4*)&bb[4]  = shv[1];
        *(float4*)&bb[8]  = shv[2]; *(float4*)&bb[12] = shv[3];
        *(float4*)&bb[16] = shv[4]; *(float4*)&bb[20] = shv[5];
        *(float4*)&bb[24] = shv[6]; *(float4*)&bb[28] = shv[7];
        float v = __expf(-dl);
        float p[16];
        powers16(v, p);
        float dlul = dl * ul;
#pragma unroll
        for (int n = 0; n < 16; ++n) q[n] = q[n] * p[n] + dlul * bb[n];
        s += dl;
        float suf = send_cd - s;
        float contrib;
        float ac[4] = {0.f, 0.f, 0.f, 0.f};
        if (suf < 0.8f) {                       // g ~= 1 (err < 4e-7)
#pragma unroll
            for (int n = 0; n < 16; ++n) ac[n & 3] += q[n] * bb[16 + n];
            contrib = (ac[0] + ac[1]) + (ac[2] + ac[3]);
        } else {
            float w = __expf(-suf);
            float e[16];
            powers16(w, e);
            if (suf > 40.f) {                   // el << eps: g = el*1e12 (err < 5e-6)
#pragma unroll
                for (int n = 0; n < 16; ++n) ac[n & 3] += (q[n] * e[n]) * bb[16 + n];
                contrib = ((ac[0] + ac[1]) + (ac[2] + ac[3])) * 1e12f;
            } else {                            // exact transition band (~3%)
#pragma unroll
                for (int n = 0; n < 16; ++n) {
                    float g = e[n] * rcpf(e[n] + 1e-12f);
                    ac[n & 3] += (q[n] * g) * bb[16 + n];
                }
                contrib = (ac[0] + ac[1]) + (ac[2] + ac[3]);
            }
        }
        float y = contrib + ul * Dd;
        float r = xr[(l0 + l) * 4096 + DIN + d];
        u[(l0 + l) * DIN + d] = y * swishf(r);
    }
}

extern "C" void kernel_launch(void* const* d_in, const int* in_sizes, int n_in,
                              void* d_out, int out_size, void* d_ws, size_t ws_size,
                              hipStream_t stream) {
    const float* x      = (const float*)d_in[0];
    const float* W_in   = (const float*)d_in[1];
    const float* conv_w = (const float*)d_in[2];
    const float* conv_b = (const float*)d_in[3];
    const float* W_x    = (const float*)d_in[4];
    const float* W_dt   = (const float*)d_in[5];
    const float* b_dt   = (const float*)d_in[6];
    const float* Dvec   = (const float*)d_in[7];
    const float* W_out  = (const float*)d_in[8];
    float* out = (float*)d_out;

    float* ws = (float*)d_ws;
    float* xr    = ws;                              // 8388608 f (cols 0..2047 dead after conv -> localQ home)
    float* xi    = ws + 8388608;                    // 4194304 f (u -> ygated)
    float* xdbl  = ws + 12582912;                   // 196608 f
    float* delta = ws + 12779520;                   // 4194304 f  [region D]
    float* csum  = ws + 16973824;                   // 262144 f (CCH*DIN)
    float* send  = ws + 17235968;                   // 262144 f -> ends 17498112 (< 18612224 proven)

    // overlays (time-disjoint dead-region reuse):
    u16* x_bf   = (u16*)(ws + 12779520);            // region D, dead before delta
    u16* WinT   = (u16*)(ws + 13828096);            // region D
    float* Psk  = ws + 12779520;                    // region D (after W_in gemm)
    u16* xd_bf  = (u16*)(ws + 16973824);            // csum region, dead before scanA
    u16* WdtT   = (u16*)(ws + 17039360);            // csum region, dead before scanA
    u16* y_bf   = (u16*)ws;                         // xr region (dead after scanC)
    u16* WoutT  = (u16*)(ws + 2097152);             // xr region (dead after scanC)

    // 1) casts for W_in GEMM
    cast_bf16_vec4<<<2048, 256, 0, stream>>>(x, x_bf, (L_SEQ * DMODEL) / 4);
    castT_bf16<<<dim3(4096 / 64, 1024 / 64), 256, 0, stream>>>(W_in, WinT, DMODEL, 4096);
    // 2) xr = x @ W_in  (M=2048, N=4096, K=1024) bf16 MFMA
    gemm_bf16<128, false><<<dim3(4096 / 128, L_SEQ / 128), 256, 0, stream>>>(
        x_bf, WinT, xr, nullptr, L_SEQ, 4096, DMODEL);
    // 3) xi = swish(causal_conv(xr[:, :2048]))
    conv_swish<<<(L_SEQ * DIN) / 256, 256, 0, stream>>>(xr, conv_w, conv_b, xi);
    // 4) xdbl = xi @ W_x  (split-K x8, fp32)
    gemm_f32_sk<<<dim3(2, L_SEQ / BM, 8), 256, 0, stream>>>(xi, W_x, Psk,
                                                            L_SEQ, 96, DIN, DIN, 96, 96, 256);
    reduce_sk<<<(L_SEQ * 96) / 256, 256, 0, stream>>>(Psk, xdbl);
    // 5) delta = softplus(xdbl[:, :64] @ W_dt + b_dt)  bf16 MFMA + epilogue
    cast_xd<<<(L_SEQ * DTR) / 256, 256, 0, stream>>>(xdbl, xd_bf);
    castT_bf16<<<dim3(2048 / 64, 64 / 64), 256, 0, stream>>>(W_dt, WdtT, DTR, DIN);
    gemm_bf16<128, true><<<dim3(DIN / 128, L_SEQ / 128), 256, 0, stream>>>(
        xd_bf, WdtT, delta, b_dt, L_SEQ, DIN, DTR);
    // 6) chunk-parallel scan, n-fused
    scanA<<<dim3(DIN / 256, CCH), 256, 0, stream>>>(delta, xi, xdbl, ws, csum);
    scanB<<<(DIN * NST) / 256, 256, 0, stream>>>(ws, csum, send);
    scanC<<<dim3(DIN / 256, CCH), 256, 0, stream>>>(delta, xi, xdbl, ws, send, Dvec, xr);
    // 7) out = ygated @ W_out  (M=2048, N=1024, K=2048) bf16 MFMA, BN=64
    cast_bf16_vec4<<<4096, 256, 0, stream>>>(xi, y_bf, (L_SEQ * DIN) / 4);
    castT_bf16<<<dim3(1024 / 64, 2048 / 64), 256, 0, stream>>>(W_out, WoutT, DIN, DMODEL);
    gemm_bf16<64, false><<<dim3(DMODEL / 64, L_SEQ / 128), 256, 0, stream>>>(
        y_bf, WoutT, out, nullptr, L_SEQ, DMODEL, DIN);
}

// Round 6
// 188.530 us; speedup vs baseline: 15.8110x; 1.1679x over previous
//
#include <hip/hip_runtime.h>
#include <hip/hip_bf16.h>

#define L_SEQ 2048
#define DMODEL 1024
#define DIN 2048
#define DTR 64
#define NST 16
#define CCH 128         // number of chunks
#define CHL 16          // L_SEQ / CCH

typedef unsigned short u16;
typedef __bf16 bf16x8 __attribute__((ext_vector_type(8)));
typedef float f32x4 __attribute__((ext_vector_type(4)));

__device__ inline u16 f2bf(float v) {
    __bf16 h = (__bf16)v;
    return __builtin_bit_cast(unsigned short, h);
}
__device__ inline float rcpf(float x) { return __builtin_amdgcn_rcpf(x); }
__device__ inline float swishf(float v) { return v * rcpf(1.f + __expf(-v)); }
__device__ inline float softplusf(float v) {
    return (v > 20.f) ? v : __logf(1.f + __expf(v));
}

// p[n] = v^(n+1), depth-4 multiply tree
__device__ inline void powers16(float v, float* p) {
    p[0] = v;
    p[1] = v * v;
    p[2] = p[1] * v;
    p[3] = p[1] * p[1];
    p[4] = p[3] * p[0];  p[5] = p[3] * p[1];  p[6] = p[3] * p[2];  p[7] = p[3] * p[3];
    p[8] = p[7] * p[0];  p[9] = p[7] * p[1];  p[10] = p[7] * p[2]; p[11] = p[7] * p[3];
    p[12] = p[7] * p[4]; p[13] = p[7] * p[5]; p[14] = p[7] * p[6]; p[15] = p[7] * p[7];
}

// localQ lives in the DEAD half-columns of xr
__device__ inline float* lqp(float* wsf, int idx) {
    return wsf + ((idx >> 11) << 12) + (idx & 2047);
}

// ================= bf16 MFMA GEMM: C[M,N] = A[M,K] * Bt[N,K]^T =================
template<int TBN, bool SP>
__global__ __launch_bounds__(256) void gemm_bf16(const u16* __restrict__ A,
                                                 const u16* __restrict__ Bt,
                                                 float* __restrict__ C,
                                                 const float* __restrict__ bias,
                                                 int M, int N, int K) {
    constexpr int LDSZ = (128 + TBN) * 64;
    constexpr int ROUNDS = (128 + TBN) / 32;
    constexpr int FN = TBN / 32;
    __shared__ u16 smem[2 * LDSZ];

    const int tid = threadIdx.x;
    const int lane = tid & 63;
    const int wid = tid >> 6;
    const int wm = wid >> 1;
    const int wn = wid & 1;
    const int bm = blockIdx.y * 128;
    const int bn = blockIdx.x * TBN;

    const int srow8 = lane >> 3;
    const int schunk = lane & 7;
    const int lm = lane & 15;
    const int lk = lane >> 4;

    f32x4 acc[4][FN];
#pragma unroll
    for (int i = 0; i < 4; ++i)
#pragma unroll
        for (int j = 0; j < FN; ++j) acc[i][j] = (f32x4){0.f, 0.f, 0.f, 0.f};

    auto stage = [&](int buf, int t) {
        const int k0 = t * 64;
        u16* base = smem + buf * LDSZ;
#pragma unroll
        for (int rr = 0; rr < ROUNDS; ++rr) {
            int row = rr * 32 + wid * 8;
            int grow = row + srow8;
            const u16* src;
            if (row < 128) src = A + (size_t)(bm + grow) * K + k0 + schunk * 8;
            else           src = Bt + (size_t)(bn + grow - 128) * K + k0 + schunk * 8;
            u16* dst = base + row * 64;
            __builtin_amdgcn_global_load_lds(
                (const __attribute__((address_space(1))) void*)src,
                (__attribute__((address_space(3))) void*)dst, 16, 0, 0);
        }
    };

    auto compute = [&](int buf) {
        const u16* base = smem + buf * LDSZ;
#pragma unroll
        for (int kk = 0; kk < 2; ++kk) {
            bf16x8 av[4], bv[FN];
#pragma unroll
            for (int fm = 0; fm < 4; ++fm)
                av[fm] = *(const bf16x8*)(base + (wm * 64 + fm * 16 + lm) * 64 + kk * 32 + lk * 8);
#pragma unroll
            for (int fn = 0; fn < FN; ++fn)
                bv[fn] = *(const bf16x8*)(base + (128 + wn * (TBN / 2) + fn * 16 + lm) * 64 + kk * 32 + lk * 8);
#pragma unroll
            for (int fm = 0; fm < 4; ++fm)
#pragma unroll
                for (int fn = 0; fn < FN; ++fn)
                    acc[fm][fn] = __builtin_amdgcn_mfma_f32_16x16x32_bf16(av[fm], bv[fn], acc[fm][fn], 0, 0, 0);
        }
    };

    const int nt = K / 64;
    int cur = 0;
    stage(0, 0);
    __syncthreads();
    for (int t = 0; t < nt - 1; ++t) {
        stage(cur ^ 1, t + 1);
        compute(cur);
        __syncthreads();
        cur ^= 1;
    }
    compute(cur);

#pragma unroll
    for (int fm = 0; fm < 4; ++fm) {
#pragma unroll
        for (int fn = 0; fn < FN; ++fn) {
            int col = bn + wn * (TBN / 2) + fn * 16 + lm;
#pragma unroll
            for (int j = 0; j < 4; ++j) {
                int row = bm + wm * 64 + fm * 16 + lk * 4 + j;
                float v = acc[fm][fn][j];
                if (SP) {
                    v += bias[col];
                    v = softplusf(v);
                }
                C[(size_t)row * N + col] = v;
            }
        }
    }
}

// ======== thin bf16 MFMA split-K GEMM (xi @ W_x): BM=128, TBN=32, z = K-split ========
__global__ __launch_bounds__(256) void gemm_bf16_sk(const u16* __restrict__ A, int lda,
                                                    const u16* __restrict__ Bt, int ldb,
                                                    float* __restrict__ P,
                                                    int M, int N, int K, int kc) {
    constexpr int TBN = 32;
    constexpr int LDSZ = (128 + TBN) * 64;
    constexpr int ROUNDS = (128 + TBN) / 32;
    __shared__ u16 smem[2 * LDSZ];

    const int tid = threadIdx.x;
    const int lane = tid & 63;
    const int wid = tid >> 6;
    const int wm = wid >> 1;
    const int wn = wid & 1;
    const int bm = blockIdx.y * 128;
    const int bn = blockIdx.x * TBN;
    const int kbeg = blockIdx.z * kc;
    float* Cz = P + (size_t)blockIdx.z * M * N;

    const int srow8 = lane >> 3;
    const int schunk = lane & 7;
    const int lm = lane & 15;
    const int lk = lane >> 4;

    f32x4 acc[4];
#pragma unroll
    for (int i = 0; i < 4; ++i) acc[i] = (f32x4){0.f, 0.f, 0.f, 0.f};

    auto stage = [&](int buf, int t) {
        const int k0 = kbeg + t * 64;
        u16* base = smem + buf * LDSZ;
#pragma unroll
        for (int rr = 0; rr < ROUNDS; ++rr) {
            int row = rr * 32 + wid * 8;
            int grow = row + srow8;
            const u16* src;
            if (row < 128) src = A + (size_t)(bm + grow) * lda + k0 + schunk * 8;
            else           src = Bt + (size_t)(bn + grow - 128) * ldb + k0 + schunk * 8;
            u16* dst = base + row * 64;
            __builtin_amdgcn_global_load_lds(
                (const __attribute__((address_space(1))) void*)src,
                (__attribute__((address_space(3))) void*)dst, 16, 0, 0);
        }
    };

    auto compute = [&](int buf) {
        const u16* base = smem + buf * LDSZ;
#pragma unroll
        for (int kk = 0; kk < 2; ++kk) {
            bf16x8 av[4], bv;
#pragma unroll
            for (int fm = 0; fm < 4; ++fm)
                av[fm] = *(const bf16x8*)(base + (wm * 64 + fm * 16 + lm) * 64 + kk * 32 + lk * 8);
            bv = *(const bf16x8*)(base + (128 + wn * 16 + lm) * 64 + kk * 32 + lk * 8);
#pragma unroll
            for (int fm = 0; fm < 4; ++fm)
                acc[fm] = __builtin_amdgcn_mfma_f32_16x16x32_bf16(av[fm], bv, acc[fm], 0, 0, 0);
        }
    };

    const int nt = kc / 64;
    int cur = 0;
    stage(0, 0);
    __syncthreads();
    for (int t = 0; t < nt - 1; ++t) {
        stage(cur ^ 1, t + 1);
        compute(cur);
        __syncthreads();
        cur ^= 1;
    }
    compute(cur);

#pragma unroll
    for (int fm = 0; fm < 4; ++fm) {
        int col = bn + wn * 16 + lm;
#pragma unroll
        for (int j = 0; j < 4; ++j) {
            int row = bm + wm * 64 + fm * 16 + lk * 4 + j;
            Cz[(size_t)row * N + col] = acc[fm][j];
        }
    }
}

// ================= casts =================
__global__ __launch_bounds__(256) void cast_bf16_vec4(const float* __restrict__ in,
                                                      u16* __restrict__ out, int nvec) {
    int i = blockIdx.x * 256 + threadIdx.x;
    if (i >= nvec) return;
    float4 v = ((const float4*)in)[i];
    ushort4 o;
    o.x = f2bf(v.x); o.y = f2bf(v.y); o.z = f2bf(v.z); o.w = f2bf(v.w);
    ((ushort4*)out)[i] = o;
}

// transpose + cast with bounds guards: W[K][N] fp32 -> Wt[N][K] bf16
__global__ __launch_bounds__(256) void castT_bf16(const float* __restrict__ W,
                                                  u16* __restrict__ Wt, int K, int N) {
    __shared__ u16 tile[64][65];
    int n0 = blockIdx.x * 64, k0 = blockIdx.y * 64;
    int tn = threadIdx.x & 63, t4 = threadIdx.x >> 6;
#pragma unroll
    for (int j = 0; j < 16; ++j) {
        int k = t4 + j * 4;
        if (n0 + tn < N) tile[tn][k] = f2bf(W[(size_t)(k0 + k) * N + n0 + tn]);
    }
    __syncthreads();
#pragma unroll
    for (int j = 0; j < 16; ++j) {
        int n = t4 + j * 4;
        if (n0 + n < N) Wt[(size_t)(n0 + n) * K + k0 + tn] = tile[n][tn];
    }
}

__global__ __launch_bounds__(256) void cast_xd(const float* __restrict__ xdbl,
                                               u16* __restrict__ xd) {
    int id = blockIdx.x * 256 + threadIdx.x;
    int l = id >> 6, k = id & 63;
    xd[id] = f2bf(xdbl[l * 96 + k]);
}

__global__ __launch_bounds__(256) void reduce_sk(const float* __restrict__ P,
                                                 float* __restrict__ xdbl) {
    int i = blockIdx.x * 256 + threadIdx.x;
    float s = 0.f;
#pragma unroll
    for (int z = 0; z < 8; ++z) s += P[z * (L_SEQ * 96) + i];
    xdbl[i] = s;
}

// ====== causal depthwise conv(4) + bias + swish; emits fp32 AND bf16 copies ======
__global__ __launch_bounds__(256) void conv_swish(const float* __restrict__ xr,
                                                  const float* __restrict__ cw,
                                                  const float* __restrict__ cb,
                                                  float* __restrict__ xi,
                                                  u16* __restrict__ xib) {
    int id = blockIdx.x * 256 + threadIdx.x;
    int l = id >> 11;
    int d = id & (DIN - 1);
    float acc = cb[d];
#pragma unroll
    for (int k = 0; k < 4; ++k) {
        int ls = l - 3 + k;
        if (ls >= 0) acc += xr[ls * 4096 + d] * cw[k * DIN + d];
    }
    float sw = swishf(acc);
    xi[id] = sw;
    xib[id] = f2bf(sw);
}

// ================= chunk-parallel selective scan, n-fused ========
__global__ __launch_bounds__(256) void scanA(const float* __restrict__ delta,
                                             const float* __restrict__ u,
                                             const float* __restrict__ xdbl,
                                             float* __restrict__ wsf,
                                             float* __restrict__ csum) {
    __shared__ float sh[CHL][16];
    const int tid = threadIdx.x;
    const int c = blockIdx.y;
    const int d = blockIdx.x * 256 + tid;
    const int l0 = c * CHL;
    {
        int l = tid >> 4, j = tid & 15;
        sh[l][j] = xdbl[(l0 + l) * 96 + DTR + j];
    }
    __syncthreads();
    float q[16];
#pragma unroll
    for (int n = 0; n < 16; ++n) q[n] = 0.f;
    float s = 0.f;
#pragma unroll 2
    for (int l = 0; l < CHL; ++l) {
        float dl = delta[(l0 + l) * DIN + d];
        float ul = u[(l0 + l) * DIN + d];
        float bb[16];
        const float4* shv = (const float4*)&sh[l][0];
        *(float4*)&bb[0] = shv[0];  *(float4*)&bb[4] = shv[1];
        *(float4*)&bb[8] = shv[2];  *(float4*)&bb[12] = shv[3];
        float v = __expf(-dl);
        float p[16];
        powers16(v, p);
        float dlul = dl * ul;
#pragma unroll
        for (int n = 0; n < 16; ++n) q[n] = q[n] * p[n] + dlul * bb[n];
        s += dl;
    }
    float* dst = lqp(wsf, (c * DIN + d) * 16);
    *(float4*)(dst + 0)  = make_float4(q[0], q[1], q[2], q[3]);
    *(float4*)(dst + 4)  = make_float4(q[4], q[5], q[6], q[7]);
    *(float4*)(dst + 8)  = make_float4(q[8], q[9], q[10], q[11]);
    *(float4*)(dst + 12) = make_float4(q[12], q[13], q[14], q[15]);
    csum[c * DIN + d] = s;
}

__global__ __launch_bounds__(256) void scanB(float* __restrict__ wsf,
                                             const float* __restrict__ csum,
                                             float* __restrict__ send) {
    int gid = blockIdx.x * 256 + threadIdx.x;
    int n = gid & 15;
    int d = gid >> 4;
    const float An = -(float)(n + 1);
    float q = 0.f;
#pragma unroll 4
    for (int c = 0; c < CCH; ++c) {
        float cs = csum[c * DIN + d];
        float w = __expf(An * cs);
        float* lq = lqp(wsf, (c * DIN + d) * 16 + n);
        float lv = *lq;
        *lq = q;
        q = q * w + lv;
    }
    if (n == 0) {
        double ssum = 0.0;
        for (int c = CCH - 1; c >= 0; --c) {
            ssum += (double)csum[c * DIN + d];
            send[c * DIN + d] = (float)ssum;
        }
    }
}

__global__ __launch_bounds__(256) void scanC(const float* __restrict__ delta,
                                             float* __restrict__ u,
                                             const float* __restrict__ xdbl,
                                             float* __restrict__ wsf,
                                             const float* __restrict__ send,
                                             const float* __restrict__ Dvec,
                                             const float* __restrict__ xr) {
    __shared__ float sh[CHL][32];
    const int tid = threadIdx.x;
    const int c = blockIdx.y;
    const int d = blockIdx.x * 256 + tid;
    const int l0 = c * CHL;
#pragma unroll
    for (int k = 0; k < 2; ++k) {
        int idx = tid + k * 256;
        int l = idx >> 5, j = idx & 31;
        sh[l][j] = xdbl[(l0 + l) * 96 + DTR + j];
    }
    __syncthreads();
    float q[16];
    {
        const float* src = lqp(wsf, (c * DIN + d) * 16);
        float4 t0 = *(const float4*)(src + 0);
        float4 t1 = *(const float4*)(src + 4);
        float4 t2 = *(const float4*)(src + 8);
        float4 t3 = *(const float4*)(src + 12);
        q[0] = t0.x; q[1] = t0.y; q[2] = t0.z; q[3] = t0.w;
        q[4] = t1.x; q[5] = t1.y; q[6] = t1.z; q[7] = t1.w;
        q[8] = t2.x; q[9] = t2.y; q[10] = t2.z; q[11] = t2.w;
        q[12] = t3.x; q[13] = t3.y; q[14] = t3.z; q[15] = t3.w;
    }
    const float send_cd = send[c * DIN + d];
    const float Dd = Dvec[d];
    float s = 0.f;
#pragma unroll 2
    for (int l = 0; l < CHL; ++l) {
        float dl = delta[(l0 + l) * DIN + d];
        float ul = u[(l0 + l) * DIN + d];
        float bb[32];
        const float4* shv = (const float4*)&sh[l][0];
        *(float4*)&bb[0]  = shv[0]; *(float4*)&bb[4]  = shv[1];
        *(float4*)&bb[8]  = shv[2]; *(float4*)&bb[12] = shv[3];
        *(float4*)&bb[16] = shv[4]; *(float4*)&bb[20] = shv[5];
        *(float4*)&bb[24] = shv[6]; *(float4*)&bb[28] = shv[7];
        float v = __expf(-dl);
        float p[16];
        powers16(v, p);
        float dlul = dl * ul;
#pragma unroll
        for (int n = 0; n < 16; ++n) q[n] = q[n] * p[n] + dlul * bb[n];
        s += dl;
        float suf = send_cd - s;
        float contrib;
        float ac[4] = {0.f, 0.f, 0.f, 0.f};
        if (suf < 0.8f) {
#pragma unroll
            for (int n = 0; n < 16; ++n) ac[n & 3] += q[n] * bb[16 + n];
            contrib = (ac[0] + ac[1]) + (ac[2] + ac[3]);
        } else {
            float w = __expf(-suf);
            float e[16];
            powers16(w, e);
            if (suf > 40.f) {
#pragma unroll
                for (int n = 0; n < 16; ++n) ac[n & 3] += (q[n] * e[n]) * bb[16 + n];
                contrib = ((ac[0] + ac[1]) + (ac[2] + ac[3])) * 1e12f;
            } else {
#pragma unroll
                for (int n = 0; n < 16; ++n) {
                    float g = e[n] * rcpf(e[n] + 1e-12f);
                    ac[n & 3] += (q[n] * g) * bb[16 + n];
                }
                contrib = (ac[0] + ac[1]) + (ac[2] + ac[3]);
            }
        }
        float y = contrib + ul * Dd;
        float r = xr[(l0 + l) * 4096 + DIN + d];
        u[(l0 + l) * DIN + d] = y * swishf(r);
    }
}

extern "C" void kernel_launch(void* const* d_in, const int* in_sizes, int n_in,
                              void* d_out, int out_size, void* d_ws, size_t ws_size,
                              hipStream_t stream) {
    const float* x      = (const float*)d_in[0];
    const float* W_in   = (const float*)d_in[1];
    const float* conv_w = (const float*)d_in[2];
    const float* conv_b = (const float*)d_in[3];
    const float* W_x    = (const float*)d_in[4];
    const float* W_dt   = (const float*)d_in[5];
    const float* b_dt   = (const float*)d_in[6];
    const float* Dvec   = (const float*)d_in[7];
    const float* W_out  = (const float*)d_in[8];
    float* out = (float*)d_out;

    float* ws = (float*)d_ws;
    float* xr    = ws;                              // 8388608 f (cols 0..2047 dead after conv -> localQ home)
    float* xi    = ws + 8388608;                    // 4194304 f (u -> ygated)
    float* xdbl  = ws + 12582912;                   // 196608 f
    // region D: 12779520 .. 16973824
    float* csum  = ws + 16973824;                   // 262144 f
    float* send  = ws + 17235968;                   // 262144 f
    float* WxTf  = ws + 17498112;                   // 98304 f (96*2048 u16) -> ends 17596416

    // region D overlays (time-disjoint):
    u16* x_bf   = (u16*)(ws + 12779520);            // dead after W_in GEMM
    u16* WinT   = (u16*)(ws + 13828096);            // dead after W_in GEMM
    u16* xi_bf  = (u16*)(ws + 12779520);            // written by conv, dead after W_x GEMM
    float* Psk  = ws + 14876672;                    // 1572864 f, dead after reduce_sk
    float* delta= ws + 12779520;                    // NOTE: delta reuses region D AFTER W_x GEMM? NO ->
    // delta must be its own region: keep delta in region D is WRONG (Psk/xi_bf live).
    // delta lives where it always did: we re-point below.
    (void)delta;

    float* deltaR = ws + 12779520;                  // placeholder to keep naming clear

    // ---- actual delta region: separate 4194304 f block is region D itself.
    // Timeline: xi_bf+Psk (steps 3-4b) both die before delta GEMM (step 5) writes.
    float* delta_buf = ws + 12779520;

    u16* xd_bf  = (u16*)(ws + 16973824);            // csum region, dead before scanA
    u16* WdtT   = (u16*)(ws + 17039360);            // csum region, dead before scanA
    u16* WxT    = (u16*)WxTf;
    u16* y_bf   = (u16*)ws;                         // xr region (dead after scanC)
    u16* WoutT  = (u16*)(ws + 2097152);             // xr region (dead after scanC)

    // 1) casts for W_in GEMM
    cast_bf16_vec4<<<2048, 256, 0, stream>>>(x, x_bf, (L_SEQ * DMODEL) / 4);
    castT_bf16<<<dim3(4096 / 64, 1024 / 64), 256, 0, stream>>>(W_in, WinT, DMODEL, 4096);
    // 2) xr = x @ W_in  (M=2048, N=4096, K=1024) bf16 MFMA
    gemm_bf16<128, false><<<dim3(4096 / 128, L_SEQ / 128), 256, 0, stream>>>(
        x_bf, WinT, xr, nullptr, L_SEQ, 4096, DMODEL);
    // 3) xi = swish(causal_conv(xr[:, :2048])), + bf16 copy for W_x GEMM
    conv_swish<<<(L_SEQ * DIN) / 256, 256, 0, stream>>>(xr, conv_w, conv_b, xi, xi_bf);
    // 3b) W_x -> WxT bf16 [96][2048]
    castT_bf16<<<dim3(2, 2048 / 64), 256, 0, stream>>>(W_x, WxT, DIN, 96);
    // 4) xdbl = xi @ W_x  (M=2048, N=96, K=2048) bf16 MFMA split-K x8
    gemm_bf16_sk<<<dim3(3, L_SEQ / 128, 8), 256, 0, stream>>>(
        xi_bf, DIN, WxT, DIN, Psk, L_SEQ, 96, DIN, 256);
    reduce_sk<<<(L_SEQ * 96) / 256, 256, 0, stream>>>(Psk, xdbl);
    // 5) delta = softplus(xdbl[:, :64] @ W_dt + b_dt)  bf16 MFMA + epilogue
    //    (delta_buf overlays region D; xi_bf/Psk are dead now)
    cast_xd<<<(L_SEQ * DTR) / 256, 256, 0, stream>>>(xdbl, xd_bf);
    castT_bf16<<<dim3(2048 / 64, 64 / 64), 256, 0, stream>>>(W_dt, WdtT, DTR, DIN);
    gemm_bf16<128, true><<<dim3(DIN / 128, L_SEQ / 128), 256, 0, stream>>>(
        xd_bf, WdtT, delta_buf, b_dt, L_SEQ, DIN, DTR);
    // 6) chunk-parallel scan, n-fused
    scanA<<<dim3(DIN / 256, CCH), 256, 0, stream>>>(delta_buf, xi, xdbl, ws, csum);
    scanB<<<(DIN * NST) / 256, 256, 0, stream>>>(ws, csum, send);
    scanC<<<dim3(DIN / 256, CCH), 256, 0, stream>>>(delta_buf, xi, xdbl, ws, send, Dvec, xr);
    // 7) out = ygated @ W_out  (M=2048, N=1024, K=2048) bf16 MFMA, BN=64
    cast_bf16_vec4<<<4096, 256, 0, stream>>>(xi, y_bf, (L_SEQ * DIN) / 4);
    castT_bf16<<<dim3(1024 / 64, 2048 / 64), 256, 0, stream>>>(W_out, WoutT, DIN, DMODEL);
    gemm_bf16<64, false><<<dim3(DMODEL / 64, L_SEQ / 128), 256, 0, stream>>>(
        y_bf, WoutT, out, nullptr, L_SEQ, DMODEL, DIN);
}

// Round 7
// 162.509 us; speedup vs baseline: 18.3426x; 1.1601x over previous
//
#include <hip/hip_runtime.h>
#include <hip/hip_bf16.h>

#define L_SEQ 2048
#define DMODEL 1024
#define DIN 2048
#define DTR 64
#define NST 16
#define CCH 128         // number of chunks
#define CHL 16          // L_SEQ / CCH

typedef unsigned short u16;
typedef __bf16 bf16x8 __attribute__((ext_vector_type(8)));
typedef float f32x4 __attribute__((ext_vector_type(4)));

__device__ inline u16 f2bf(float v) {
    __bf16 h = (__bf16)v;
    return __builtin_bit_cast(unsigned short, h);
}
__device__ inline float rcpf(float x) { return __builtin_amdgcn_rcpf(x); }
__device__ inline float swishf(float v) { return v * rcpf(1.f + __expf(-v)); }
__device__ inline float softplusf(float v) {
    return (v > 20.f) ? v : __logf(1.f + __expf(v));
}

// p[n] = v^(n+1), depth-4 multiply tree
__device__ inline void powers16(float v, float* p) {
    p[0] = v;
    p[1] = v * v;
    p[2] = p[1] * v;
    p[3] = p[1] * p[1];
    p[4] = p[3] * p[0];  p[5] = p[3] * p[1];  p[6] = p[3] * p[2];  p[7] = p[3] * p[3];
    p[8] = p[7] * p[0];  p[9] = p[7] * p[1];  p[10] = p[7] * p[2]; p[11] = p[7] * p[3];
    p[12] = p[7] * p[4]; p[13] = p[7] * p[5]; p[14] = p[7] * p[6]; p[15] = p[7] * p[7];
}

// ================= bf16 MFMA GEMM: C[M,N] = A[M,K] * Bt[N,K]^T =================
template<int TBN, bool SP>
__global__ __launch_bounds__(256) void gemm_bf16(const u16* __restrict__ A,
                                                 const u16* __restrict__ Bt,
                                                 float* __restrict__ C,
                                                 const float* __restrict__ bias,
                                                 int M, int N, int K) {
    constexpr int LDSZ = (128 + TBN) * 64;
    constexpr int ROUNDS = (128 + TBN) / 32;
    constexpr int FN = TBN / 32;
    __shared__ u16 smem[2 * LDSZ];

    const int tid = threadIdx.x;
    const int lane = tid & 63;
    const int wid = tid >> 6;
    const int wm = wid >> 1;
    const int wn = wid & 1;
    const int bm = blockIdx.y * 128;
    const int bn = blockIdx.x * TBN;

    const int srow8 = lane >> 3;
    const int schunk = lane & 7;
    const int lm = lane & 15;
    const int lk = lane >> 4;

    f32x4 acc[4][FN];
#pragma unroll
    for (int i = 0; i < 4; ++i)
#pragma unroll
        for (int j = 0; j < FN; ++j) acc[i][j] = (f32x4){0.f, 0.f, 0.f, 0.f};

    auto stage = [&](int buf, int t) {
        const int k0 = t * 64;
        u16* base = smem + buf * LDSZ;
#pragma unroll
        for (int rr = 0; rr < ROUNDS; ++rr) {
            int row = rr * 32 + wid * 8;
            int grow = row + srow8;
            const u16* src;
            if (row < 128) src = A + (size_t)(bm + grow) * K + k0 + schunk * 8;
            else           src = Bt + (size_t)(bn + grow - 128) * K + k0 + schunk * 8;
            u16* dst = base + row * 64;
            __builtin_amdgcn_global_load_lds(
                (const __attribute__((address_space(1))) void*)src,
                (__attribute__((address_space(3))) void*)dst, 16, 0, 0);
        }
    };

    auto compute = [&](int buf) {
        const u16* base = smem + buf * LDSZ;
#pragma unroll
        for (int kk = 0; kk < 2; ++kk) {
            bf16x8 av[4], bv[FN];
#pragma unroll
            for (int fm = 0; fm < 4; ++fm)
                av[fm] = *(const bf16x8*)(base + (wm * 64 + fm * 16 + lm) * 64 + kk * 32 + lk * 8);
#pragma unroll
            for (int fn = 0; fn < FN; ++fn)
                bv[fn] = *(const bf16x8*)(base + (128 + wn * (TBN / 2) + fn * 16 + lm) * 64 + kk * 32 + lk * 8);
#pragma unroll
            for (int fm = 0; fm < 4; ++fm)
#pragma unroll
                for (int fn = 0; fn < FN; ++fn)
                    acc[fm][fn] = __builtin_amdgcn_mfma_f32_16x16x32_bf16(av[fm], bv[fn], acc[fm][fn], 0, 0, 0);
        }
    };

    const int nt = K / 64;
    int cur = 0;
    stage(0, 0);
    __syncthreads();
    for (int t = 0; t < nt - 1; ++t) {
        stage(cur ^ 1, t + 1);
        compute(cur);
        __syncthreads();
        cur ^= 1;
    }
    compute(cur);

#pragma unroll
    for (int fm = 0; fm < 4; ++fm) {
#pragma unroll
        for (int fn = 0; fn < FN; ++fn) {
            int col = bn + wn * (TBN / 2) + fn * 16 + lm;
#pragma unroll
            for (int j = 0; j < 4; ++j) {
                int row = bm + wm * 64 + fm * 16 + lk * 4 + j;
                float v = acc[fm][fn][j];
                if (SP) {
                    v += bias[col];
                    v = softplusf(v);
                }
                C[(size_t)row * N + col] = v;
            }
        }
    }
}

// ======== thin bf16 MFMA split-K GEMM (xi @ W_x): BM=128, TBN=32, z = K-split ========
__global__ __launch_bounds__(256) void gemm_bf16_sk(const u16* __restrict__ A, int lda,
                                                    const u16* __restrict__ Bt, int ldb,
                                                    float* __restrict__ P,
                                                    int M, int N, int K, int kc) {
    constexpr int TBN = 32;
    constexpr int LDSZ = (128 + TBN) * 64;
    constexpr int ROUNDS = (128 + TBN) / 32;
    __shared__ u16 smem[2 * LDSZ];

    const int tid = threadIdx.x;
    const int lane = tid & 63;
    const int wid = tid >> 6;
    const int wm = wid >> 1;
    const int wn = wid & 1;
    const int bm = blockIdx.y * 128;
    const int bn = blockIdx.x * TBN;
    const int kbeg = blockIdx.z * kc;
    float* Cz = P + (size_t)blockIdx.z * M * N;

    const int srow8 = lane >> 3;
    const int schunk = lane & 7;
    const int lm = lane & 15;
    const int lk = lane >> 4;

    f32x4 acc[4];
#pragma unroll
    for (int i = 0; i < 4; ++i) acc[i] = (f32x4){0.f, 0.f, 0.f, 0.f};

    auto stage = [&](int buf, int t) {
        const int k0 = kbeg + t * 64;
        u16* base = smem + buf * LDSZ;
#pragma unroll
        for (int rr = 0; rr < ROUNDS; ++rr) {
            int row = rr * 32 + wid * 8;
            int grow = row + srow8;
            const u16* src;
            if (row < 128) src = A + (size_t)(bm + grow) * lda + k0 + schunk * 8;
            else           src = Bt + (size_t)(bn + grow - 128) * ldb + k0 + schunk * 8;
            u16* dst = base + row * 64;
            __builtin_amdgcn_global_load_lds(
                (const __attribute__((address_space(1))) void*)src,
                (__attribute__((address_space(3))) void*)dst, 16, 0, 0);
        }
    };

    auto compute = [&](int buf) {
        const u16* base = smem + buf * LDSZ;
#pragma unroll
        for (int kk = 0; kk < 2; ++kk) {
            bf16x8 av[4], bv;
#pragma unroll
            for (int fm = 0; fm < 4; ++fm)
                av[fm] = *(const bf16x8*)(base + (wm * 64 + fm * 16 + lm) * 64 + kk * 32 + lk * 8);
            bv = *(const bf16x8*)(base + (128 + wn * 16 + lm) * 64 + kk * 32 + lk * 8);
#pragma unroll
            for (int fm = 0; fm < 4; ++fm)
                acc[fm] = __builtin_amdgcn_mfma_f32_16x16x32_bf16(av[fm], bv, acc[fm], 0, 0, 0);
        }
    };

    const int nt = kc / 64;
    int cur = 0;
    stage(0, 0);
    __syncthreads();
    for (int t = 0; t < nt - 1; ++t) {
        stage(cur ^ 1, t + 1);
        compute(cur);
        __syncthreads();
        cur ^= 1;
    }
    compute(cur);

#pragma unroll
    for (int fm = 0; fm < 4; ++fm) {
        int col = bn + wn * 16 + lm;
#pragma unroll
        for (int j = 0; j < 4; ++j) {
            int row = bm + wm * 64 + fm * 16 + lk * 4 + j;
            Cz[(size_t)row * N + col] = acc[fm][j];
        }
    }
}

// ================= fused input prep: x cast + 4 weight transpose-casts =================
__device__ inline void castT_dev(const float* __restrict__ W, u16* __restrict__ Wt,
                                 int K, int N, int bx, int by) {
    __shared__ u16 tile[64][65];
    int n0 = bx * 64, k0 = by * 64;
    int tn = threadIdx.x & 63, t4 = threadIdx.x >> 6;
#pragma unroll
    for (int j = 0; j < 16; ++j) {
        int k = t4 + j * 4;
        if (n0 + tn < N) tile[tn][k] = f2bf(W[(size_t)(k0 + k) * N + n0 + tn]);
    }
    __syncthreads();
#pragma unroll
    for (int j = 0; j < 16; ++j) {
        int n = t4 + j * 4;
        if (n0 + n < N) Wt[(size_t)(n0 + n) * K + k0 + tn] = tile[n][tn];
    }
}

__global__ __launch_bounds__(256) void prep_fused(const float* __restrict__ x,
                                                  const float* __restrict__ W_in,
                                                  const float* __restrict__ W_x,
                                                  const float* __restrict__ W_dt,
                                                  const float* __restrict__ W_out,
                                                  u16* __restrict__ xbf,
                                                  u16* __restrict__ WinT,
                                                  u16* __restrict__ WxT,
                                                  u16* __restrict__ WdtT,
                                                  u16* __restrict__ WoutT) {
    int b = blockIdx.x;
    if (b < 2048) {                         // x -> bf16 (float4-wide)
        int i = b * 256 + threadIdx.x;      // < 524288 float4s
        float4 v = ((const float4*)x)[i];
        ushort4 o;
        o.x = f2bf(v.x); o.y = f2bf(v.y); o.z = f2bf(v.z); o.w = f2bf(v.w);
        ((ushort4*)xbf)[i] = o;
    } else if (b < 3072) {                  // W_in [1024][4096] -> WinT [4096][1024]
        int t = b - 2048;                   // nx=64, ny=16
        castT_dev(W_in, WinT, DMODEL, 4096, t & 63, t >> 6);
    } else if (b < 3136) {                  // W_x [2048][96] -> WxT [96][2048]
        int t = b - 3072;                   // nx=2, ny=32
        castT_dev(W_x, WxT, DIN, 96, t & 1, t >> 1);
    } else if (b < 3168) {                  // W_dt [64][2048] -> WdtT [2048][64]
        int t = b - 3136;                   // nx=32, ny=1
        castT_dev(W_dt, WdtT, DTR, DIN, t, 0);
    } else {                                // W_out [2048][1024] -> WoutT [1024][2048]
        int t = b - 3168;                   // nx=16, ny=32
        castT_dev(W_out, WoutT, DIN, DMODEL, t & 15, t >> 4);
    }
}

// ======== split-K reduce + fused bf16 cast of delta-rank columns ========
__global__ __launch_bounds__(256) void reduce_sk(const float* __restrict__ P,
                                                 float* __restrict__ xdbl,
                                                 u16* __restrict__ xdbf) {
    int i = blockIdx.x * 256 + threadIdx.x;   // < 2048*96
    float s = 0.f;
#pragma unroll
    for (int z = 0; z < 8; ++z) s += P[z * (L_SEQ * 96) + i];
    xdbl[i] = s;
    int l = i / 96, k = i - l * 96;
    if (k < DTR) xdbf[l * DTR + k] = f2bf(s);
}

// ====== causal depthwise conv(4) + bias + swish; emits fp32 AND bf16 copies ======
__global__ __launch_bounds__(256) void conv_swish(const float* __restrict__ xr,
                                                  const float* __restrict__ cw,
                                                  const float* __restrict__ cb,
                                                  float* __restrict__ xi,
                                                  u16* __restrict__ xib) {
    int id = blockIdx.x * 256 + threadIdx.x;
    int l = id >> 11;
    int d = id & (DIN - 1);
    float acc = cb[d];
#pragma unroll
    for (int k = 0; k < 4; ++k) {
        int ls = l - 3 + k;
        if (ls >= 0) acc += xr[ls * 4096 + d] * cw[k * DIN + d];
    }
    float sw = swishf(acc);
    xi[id] = sw;
    xib[id] = f2bf(sw);
}

// ================= chunk-parallel selective scan, n-fused ========
__global__ __launch_bounds__(256) void scanA(const float* __restrict__ delta,
                                             const float* __restrict__ u,
                                             const float* __restrict__ xdbl,
                                             float* __restrict__ localQ,
                                             float* __restrict__ csum) {
    __shared__ float sh[CHL][16];
    const int tid = threadIdx.x;
    const int c = blockIdx.y;
    const int d = blockIdx.x * 256 + tid;
    const int l0 = c * CHL;
    {
        int l = tid >> 4, j = tid & 15;
        sh[l][j] = xdbl[(l0 + l) * 96 + DTR + j];
    }
    __syncthreads();
    float q[16];
#pragma unroll
    for (int n = 0; n < 16; ++n) q[n] = 0.f;
    float s = 0.f;
#pragma unroll 2
    for (int l = 0; l < CHL; ++l) {
        float dl = delta[(l0 + l) * DIN + d];
        float ul = u[(l0 + l) * DIN + d];
        float bb[16];
        const float4* shv = (const float4*)&sh[l][0];
        *(float4*)&bb[0] = shv[0];  *(float4*)&bb[4] = shv[1];
        *(float4*)&bb[8] = shv[2];  *(float4*)&bb[12] = shv[3];
        float v = __expf(-dl);
        float p[16];
        powers16(v, p);
        float dlul = dl * ul;
#pragma unroll
        for (int n = 0; n < 16; ++n) q[n] = q[n] * p[n] + dlul * bb[n];
        s += dl;
    }
    float* dst = localQ + (size_t)(c * DIN + d) * 16;
    *(float4*)(dst + 0)  = make_float4(q[0], q[1], q[2], q[3]);
    *(float4*)(dst + 4)  = make_float4(q[4], q[5], q[6], q[7]);
    *(float4*)(dst + 8)  = make_float4(q[8], q[9], q[10], q[11]);
    *(float4*)(dst + 12) = make_float4(q[12], q[13], q[14], q[15]);
    csum[c * DIN + d] = s;
}

__global__ __launch_bounds__(256) void scanB(float* __restrict__ localQ,
                                             const float* __restrict__ csum,
                                             float* __restrict__ send) {
    int gid = blockIdx.x * 256 + threadIdx.x;
    int n = gid & 15;
    int d = gid >> 4;
    const float An = -(float)(n + 1);
    float q = 0.f;
#pragma unroll 4
    for (int c = 0; c < CCH; ++c) {
        float cs = csum[c * DIN + d];
        float w = __expf(An * cs);
        float* lq = localQ + (size_t)(c * DIN + d) * 16 + n;
        float lv = *lq;
        *lq = q;                 // qstart for chunk c
        q = q * w + lv;
    }
    if (n == 0) {
        double ssum = 0.0;
        for (int c = CCH - 1; c >= 0; --c) {
            ssum += (double)csum[c * DIN + d];
            send[c * DIN + d] = (float)ssum;
        }
    }
}

__global__ __launch_bounds__(256) void scanC(const float* __restrict__ delta,
                                             const float* __restrict__ u,
                                             const float* __restrict__ xdbl,
                                             const float* __restrict__ localQ,
                                             const float* __restrict__ send,
                                             const float* __restrict__ Dvec,
                                             const float* __restrict__ xr,
                                             u16* __restrict__ ybf) {
    __shared__ float sh[CHL][32];
    const int tid = threadIdx.x;
    const int c = blockIdx.y;
    const int d = blockIdx.x * 256 + tid;
    const int l0 = c * CHL;
#pragma unroll
    for (int k = 0; k < 2; ++k) {
        int idx = tid + k * 256;
        int l = idx >> 5, j = idx & 31;
        sh[l][j] = xdbl[(l0 + l) * 96 + DTR + j];
    }
    __syncthreads();
    float q[16];
    {
        const float* src = localQ + (size_t)(c * DIN + d) * 16;
        float4 t0 = *(const float4*)(src + 0);
        float4 t1 = *(const float4*)(src + 4);
        float4 t2 = *(const float4*)(src + 8);
        float4 t3 = *(const float4*)(src + 12);
        q[0] = t0.x; q[1] = t0.y; q[2] = t0.z; q[3] = t0.w;
        q[4] = t1.x; q[5] = t1.y; q[6] = t1.z; q[7] = t1.w;
        q[8] = t2.x; q[9] = t2.y; q[10] = t2.z; q[11] = t2.w;
        q[12] = t3.x; q[13] = t3.y; q[14] = t3.z; q[15] = t3.w;
    }
    const float send_cd = send[c * DIN + d];
    const float Dd = Dvec[d];
    float s = 0.f;
#pragma unroll 2
    for (int l = 0; l < CHL; ++l) {
        float dl = delta[(l0 + l) * DIN + d];
        float ul = u[(l0 + l) * DIN + d];
        float bb[32];
        const float4* shv = (const float4*)&sh[l][0];
        *(float4*)&bb[0]  = shv[0]; *(float4*)&bb[4]  = shv[1];
        *(float4*)&bb[8]  = shv[2]; *(float4*)&bb[12] = shv[3];
        *(float4*)&bb[16] = shv[4]; *(float4*)&bb[20] = shv[5];
        *(float4*)&bb[24] = shv[6]; *(float4*)&bb[28] = shv[7];
        float v = __expf(-dl);
        float p[16];
        powers16(v, p);
        float dlul = dl * ul;
#pragma unroll
        for (int n = 0; n < 16; ++n) q[n] = q[n] * p[n] + dlul * bb[n];
        s += dl;
        float suf = send_cd - s;
        float contrib;
        float ac[4] = {0.f, 0.f, 0.f, 0.f};
        if (suf < 0.8f) {                       // g ~= 1 (err < 4e-7)
#pragma unroll
            for (int n = 0; n < 16; ++n) ac[n & 3] += q[n] * bb[16 + n];
            contrib = (ac[0] + ac[1]) + (ac[2] + ac[3]);
        } else {
            float w = __expf(-suf);
            float e[16];
            powers16(w, e);
            if (suf > 40.f) {                   // el << eps: g = el*1e12
#pragma unroll
                for (int n = 0; n < 16; ++n) ac[n & 3] += (q[n] * e[n]) * bb[16 + n];
                contrib = ((ac[0] + ac[1]) + (ac[2] + ac[3])) * 1e12f;
            } else {                            // exact transition band
#pragma unroll
                for (int n = 0; n < 16; ++n) {
                    float g = e[n] * rcpf(e[n] + 1e-12f);
                    ac[n & 3] += (q[n] * g) * bb[16 + n];
                }
                contrib = (ac[0] + ac[1]) + (ac[2] + ac[3]);
            }
        }
        float y = contrib + ul * Dd;
        float r = xr[(l0 + l) * 4096 + DIN + d];
        ybf[(l0 + l) * DIN + d] = f2bf(y * swishf(r));   // direct bf16 for W_out GEMM
    }
}

extern "C" void kernel_launch(void* const* d_in, const int* in_sizes, int n_in,
                              void* d_out, int out_size, void* d_ws, size_t ws_size,
                              hipStream_t stream) {
    const float* x      = (const float*)d_in[0];
    const float* W_in   = (const float*)d_in[1];
    const float* conv_w = (const float*)d_in[2];
    const float* conv_b = (const float*)d_in[3];
    const float* W_x    = (const float*)d_in[4];
    const float* W_dt   = (const float*)d_in[5];
    const float* b_dt   = (const float*)d_in[6];
    const float* Dvec   = (const float*)d_in[7];
    const float* W_out  = (const float*)d_in[8];
    float* out = (float*)d_out;

    // ws_size = 256 MiB (observed via harness poison fill WRITE_SIZE = 262144 KB).
    // Clean dedicated layout, 127.5 MB total, no overlays:
    float* ws = (float*)d_ws;
    float* xr     = ws;                 // 8388608 f  (2048 x 4096)
    float* xi     = ws + 8388608;       // 4194304 f  (u, fp32)
    u16*   xibf   = (u16*)(ws + 12582912);  // 2048*2048 u16 (2097152 f)
    float* xdbl   = ws + 14680064;      // 196608 f
    float* delta  = ws + 14876672;      // 4194304 f
    float* localQ = ws + 19070976;      // 4194304 f
    float* csum   = ws + 23265280;      // 262144 f
    float* send   = ws + 23527424;      // 262144 f
    u16*   xbf    = (u16*)(ws + 23789568);  // 2048*1024 u16 (1048576 f)
    u16*   WinT   = (u16*)(ws + 24838144);  // 4096*1024 u16 (2097152 f)
    u16*   WxT    = (u16*)(ws + 26935296);  // 96*2048 u16 (98304 f)
    u16*   WdtT   = (u16*)(ws + 27033600);  // 2048*64 u16 (65536 f)
    u16*   WoutT  = (u16*)(ws + 27099136);  // 1024*2048 u16 (1048576 f)
    u16*   xdbf   = (u16*)(ws + 28147712);  // 2048*64 u16 (65536 f)
    float* Psk    = ws + 28213248;      // 1572864 f (8*2048*96)
    u16*   ybf    = (u16*)(ws + 29786112);  // 2048*2048 u16 (2097152 f) -> end 31883264 f

    // 1) fused prep: x->bf16 + all 4 weight transpose-casts (1 launch)
    prep_fused<<<3680, 256, 0, stream>>>(x, W_in, W_x, W_dt, W_out,
                                         xbf, WinT, WxT, WdtT, WoutT);
    // 2) xr = x @ W_in  (M=2048, N=4096, K=1024) bf16 MFMA
    gemm_bf16<128, false><<<dim3(4096 / 128, L_SEQ / 128), 256, 0, stream>>>(
        xbf, WinT, xr, nullptr, L_SEQ, 4096, DMODEL);
    // 3) xi = swish(causal_conv(xr[:, :2048])), fp32 + bf16
    conv_swish<<<(L_SEQ * DIN) / 256, 256, 0, stream>>>(xr, conv_w, conv_b, xi, xibf);
    // 4) xdbl = xi @ W_x  (M=2048, N=96, K=2048) bf16 MFMA split-K x8 + reduce(+cast)
    gemm_bf16_sk<<<dim3(3, L_SEQ / 128, 8), 256, 0, stream>>>(
        xibf, DIN, WxT, DIN, Psk, L_SEQ, 96, DIN, 256);
    reduce_sk<<<(L_SEQ * 96) / 256, 256, 0, stream>>>(Psk, xdbl, xdbf);
    // 5) delta = softplus(xdbl[:, :64] @ W_dt + b_dt)  bf16 MFMA + epilogue
    gemm_bf16<128, true><<<dim3(DIN / 128, L_SEQ / 128), 256, 0, stream>>>(
        xdbf, WdtT, delta, b_dt, L_SEQ, DIN, DTR);
    // 6) chunk-parallel scan, n-fused; scanC writes ybf directly
    scanA<<<dim3(DIN / 256, CCH), 256, 0, stream>>>(delta, xi, xdbl, localQ, csum);
    scanB<<<(DIN * NST) / 256, 256, 0, stream>>>(localQ, csum, send);
    scanC<<<dim3(DIN / 256, CCH), 256, 0, stream>>>(delta, xi, xdbl, localQ, send,
                                                    Dvec, xr, ybf);
    // 7) out = ygated @ W_out  (M=2048, N=1024, K=2048) bf16 MFMA, BN=64
    gemm_bf16<64, false><<<dim3(DMODEL / 64, L_SEQ / 128), 256, 0, stream>>>(
        ybf, WoutT, out, nullptr, L_SEQ, DMODEL, DIN);
}